// Round 10
// baseline (75.611 us; speedup 1.0000x reference)
//
#include <hip/hip_runtime.h>
#include <math.h>

#define NPTS  524288
#define NRAYS 4096
#define ACT_SHIFT_F (-2.1972245773362196f)   // log(1/(1-0.1) - 1)
#define INTERVAL_F  0.5f

typedef _Float16 f16x8  __attribute__((ext_vector_type(8)));
typedef __fp16   fp16x2 __attribute__((ext_vector_type(2)));
typedef float    f32x4  __attribute__((ext_vector_type(4)));
typedef float    f32x16 __attribute__((ext_vector_type(16)));
typedef int      i32x2  __attribute__((ext_vector_type(2)));
typedef unsigned u32;
typedef unsigned u32x4  __attribute__((ext_vector_type(4)));

#define MFMA32(a,b,c) __builtin_amdgcn_mfma_f32_32x32x16_f16((a),(b),(c),0,0,0)

// ---- pool layout (halves). Weights [of][Kpad] f16.
// emb slots: [x,y,z,1,(s,s,s,c,c,c)*5] (34 used, K=48); slot3=1 drives bias rows
// of wb0/wa0 (row k=3). vemb slot3=1 drives wview row 67.
#define WB0T_OFF   0        // 64 x 48
#define WB1T_OFF   3072     // 64 x 64
#define WB2T_OFF   7168     // 64 x 64
#define WA0T_OFF   11264    // 64 x 112 (k<48: emb block incl bias row3, 48..111: h2)
#define WA1T_OFF   18432    // 64 x 64
#define WA2T_OFF   22528    // 64 x 64
#define WLATT_OFF  26624    // 64 x 64
#define WVIEWT_OFF 30720    // 32 x 96
#define WC0T_OFF   33792    // 32 x 32
#define WEND_H     34816
// bias table f32: 5 dense layers x 64 (C-frag order) + c0 16 + pad = 384 f32
#define BTAB_H     34816
#define BTAB_F32   384
#define VTAB_OFF   (34816 + 768)           // 4096 rays x 32 halves
#define RAYTAB_H   (VTAB_OFF + NRAYS*32)   // (NRAYS+1) ints
#define PREP_W     34816
#define PREP_BT    (PREP_W + BTAB_F32)     // 35200
#define PREP_IDS   (PREP_BT + NRAYS)       // 39296
#define PREP_TOTAL (PREP_IDS + NPTS)

// LDS: 4 emb fragments [fi:4][p:64] x 16B + w16[64]
#define SMEM_W (4*64*4 + 64)   // 1088 u32 = 4352 B

// ================= helpers ==================================================
__device__ __forceinline__ u32 pk(float a, float b) {
    fp16x2 h = __builtin_amdgcn_cvt_pkrtz(a, b);
    return __builtin_bit_cast(u32, h);
}

__device__ __forceinline__ void plswap(u32 &x, u32 &y) {
    i32x2 r = __builtin_amdgcn_permlane32_swap((int)x, (int)y, false, false);
    x = (u32)r[0]; y = (u32)r[1];
}

__device__ __forceinline__ f32x16 zero16() {
    f32x16 z;
#pragma unroll
    for (int i = 0; i < 16; ++i) z[i] = 0.f;
    return z;
}

template<bool RELU>
__device__ __forceinline__ f16x8 reluq(f16x8 v) {
    if (RELU) {
        f16x8 z = {};
        return __builtin_elementwise_max(v, z);   // v_pk_max_f16 x4
    }
    return v;
}

// D(32x32 tile) -> two B k-chunk fragments of next layer (HW-verified r5-r9);
// relu post-pack (rtz sign-preserving => identical)
template<bool RELU>
__device__ __forceinline__ void d2b(f32x16 a, f16x8 &blo, f16x8 &bhi) {
    u32 p0 = pk(a[0],a[1]),   p1 = pk(a[2],a[3]);
    u32 p2 = pk(a[4],a[5]),   p3 = pk(a[6],a[7]);
    plswap(p0, p2); plswap(p1, p3);
    u32x4 lo = {p0, p1, p2, p3};
    blo = reluq<RELU>(__builtin_bit_cast(f16x8, lo));
    u32 p4 = pk(a[8],a[9]),   p5 = pk(a[10],a[11]);
    u32 p6 = pk(a[12],a[13]), p7 = pk(a[14],a[15]);
    plswap(p4, p6); plswap(p5, p7);
    u32x4 hw = {p4, p5, p6, p7};
    bhi = reluq<RELU>(__builtin_bit_cast(f16x8, hw));
}

// ================= prep: weights + btab + vemb table + ray-start table ======
extern "C" __global__ void __launch_bounds__(256)
prep_weights(const float* __restrict__ wb0, const float* __restrict__ bb0,
             const float* __restrict__ wb1, const float* __restrict__ bb1,
             const float* __restrict__ wb2, const float* __restrict__ bb2,
             const float* __restrict__ wa0, const float* __restrict__ ba0,
             const float* __restrict__ wa1, const float* __restrict__ ba1,
             const float* __restrict__ wa2, const float* __restrict__ ba2,
             const float* __restrict__ wlat, const float* __restrict__ blat,
             const float* __restrict__ wview, const float* __restrict__ bview,
             const float* __restrict__ wc0, const float* __restrict__ bc0,
             const float* __restrict__ view, const int* __restrict__ ray_id,
             _Float16* __restrict__ pool)
{
    const int id = blockIdx.x * 256 + threadIdx.x;
    if (id >= PREP_TOTAL) return;

    if (id < PREP_W) {
        int r = id; float v = 0.f;
        if (r < 3072) {                       // WB0 64x48
            int n = r / 48, k = r % 48;
            if (k < 3) v = wb0[k*64+n]; else if (k == 3) v = bb0[n];
            else if (k < 34) v = wb0[(k-1)*64+n];
        } else if (r < 7168) { r -= 3072; int n=r>>6, k=r&63; v = wb1[k*64+n];
        } else if (r < 11264) { r -= 7168; int n=r>>6, k=r&63; v = wb2[k*64+n];
        } else if (r < 18432) { r -= 11264;   // WA0 64x112
            int n = r / 112, k = r % 112;
            if (k < 3) v = wa0[k*64+n]; else if (k == 3) v = ba0[n];
            else if (k < 34) v = wa0[(k-1)*64+n];
            else if (k >= 48) v = wa0[(k-15)*64+n];   // 33 + (k-48)
        } else if (r < 22528) { r -= 18432; int n=r>>6, k=r&63; v = wa1[k*64+n];
        } else if (r < 26624) { r -= 22528; int n=r>>6, k=r&63; v = wa2[k*64+n];
        } else if (r < 30720) { r -= 26624; int n=r>>6, k=r&63; v = wlat[k*64+n];
        } else if (r < 33792) { r -= 30720;   // WVIEW 32x96
            int n = r / 96, k = r % 96;
            if (k < 64) v = wview[k*32+n];
            else { int s = k - 64;
                   if (s < 3) v = wview[(64+s)*32+n];
                   else if (s == 3) v = bview[n];
                   else if (s < 22) v = wview[(63+s)*32+n]; }
        } else { r -= 33792;                  // WC0 32x32 (of>=16 zero)
            int n = r >> 5, k = r & 31;
            if (n < 16) v = wc0[k*16+n];
        }
        pool[id] = (_Float16)v;
        return;
    }

    if (id < PREP_BT) {                       // bias table, f32, C-frag order
        float* bt = (float*)(pool + BTAB_H);
        const int e = id - PREP_W; float v = 0.f;
        if (e < 320) {
            int l = e >> 6, rem = e & 63;
            int mt = rem >> 5, hi2 = (rem >> 4) & 1, q = rem & 15;
            int row = (q & 3) + 8*(q >> 2) + 4*hi2 + 32*mt;
            const float* src[5] = { bb1, bb2, ba1, ba2, blat };
            v = src[l][row];
        } else if (e < 336) {
            int t = e - 320, hi2 = t >> 3, q = t & 7;
            int row = (q & 3) + 8*(q >> 2) + 4*hi2;
            v = bc0[row];
        }
        bt[e] = v;
        return;
    }

    if (id < PREP_IDS) {
        // per-ray vemb row: [vx,vy,vz,1, (s,s,s,c,c,c)*3, 0-pad..31]
        const int ray = id - PREP_BT;
        const float vx = view[3*ray+0], vy = view[3*ray+1], vz = view[3*ray+2];
        u32 w_[16];
        w_[0] = pk(vx, vy); w_[1] = pk(vz, 1.0f);   // slot3 = 1 -> bias row 67
#pragma unroll
        for (int f = 0; f < 3; ++f) {
            const float fac = (float)(1 << f);
            float sx = __sinf(fac*vx), cx = __cosf(fac*vx);
            float sy = __sinf(fac*vy), cy = __cosf(fac*vy);
            float sz = __sinf(fac*vz), cz = __cosf(fac*vz);
            w_[2+3*f+0] = pk(sx,sy); w_[2+3*f+1] = pk(sz,cx); w_[2+3*f+2] = pk(cy,cz);
        }
#pragma unroll
        for (int i = 11; i < 16; ++i) w_[i] = 0u;
        u32* dst = (u32*)(pool + VTAB_OFF) + ray * 16;
#pragma unroll
        for (int i = 0; i < 4; ++i)
            ((u32x4*)dst)[i] = (u32x4){w_[4*i], w_[4*i+1], w_[4*i+2], w_[4*i+3]};
        return;
    }

    // ray-start table from sorted ray_id
    {
        const int p = id - PREP_IDS;          // 0..NPTS-1
        int* tab = (int*)(pool + RAYTAB_H);
        const int cur  = ray_id[p];
        const int prev = (p == 0) ? -1 : ray_id[p-1];
        for (int r = prev + 1; r <= cur; ++r) tab[r] = p;
        if (p == NPTS - 1)
            for (int r = cur + 1; r <= NRAYS; ++r) tab[r] = NPTS;
    }
}

// ================= load / compute helpers ===================================
template<int NKC, int KPAD>
__device__ __forceinline__ void loadWn(f16x8 (&W)[2][NKC], const _Float16* __restrict__ wT,
                                       int col, int hi) {
#pragma unroll
    for (int mt = 0; mt < 2; ++mt)
#pragma unroll
        for (int kc = 0; kc < NKC; ++kc)
            W[mt][kc] = *(const f16x8*)(wT + (mt*32 + col)*KPAD + kc*16 + hi*8);
}

__device__ __forceinline__ void loadBV(f32x16 (&bv)[2], const float* __restrict__ bt,
                                       int l, int hi) {
#pragma unroll
    for (int mt = 0; mt < 2; ++mt) {
        const float* p = bt + l*64 + (mt*2 + hi)*16;
#pragma unroll
        for (int i = 0; i < 4; ++i) {
            f32x4 v = *(const f32x4*)(p + 4*i);
#pragma unroll
            for (int s = 0; s < 4; ++s) bv[mt][4*i + s] = v[s];
        }
    }
}

// dense 64->64: single W buffer, bias as C-init (2 col-tiles / 64 pts)
template<bool RELU>
__device__ __forceinline__ void dense2(const f16x8 (&W)[2][4], const f32x16 (&bv)[2],
                                       f16x8 (&b)[2][4]) {
#pragma unroll
    for (int t = 0; t < 2; ++t) {
        f32x16 a0 = MFMA32(W[0][0], b[t][0], bv[0]);
        f32x16 a1 = MFMA32(W[1][0], b[t][0], bv[1]);
#pragma unroll
        for (int kc = 1; kc < 4; ++kc) {
            a0 = MFMA32(W[0][kc], b[t][kc], a0);
            a1 = MFMA32(W[1][kc], b[t][kc], a1);
        }
        d2b<RELU>(a0, b[t][0], b[t][1]);
        d2b<RELU>(a1, b[t][2], b[t][3]);
    }
}

// ================= fused MLP: 1 wave (64 thr) = 64 points ===================
// (64,2): min 2 waves/EU; per-wave state sized to fit 256 unified regs
extern "C" __global__ void __launch_bounds__(64, 2)
mlp_mfma(const float* __restrict__ coor, const int* __restrict__ ray_id,
         const float* __restrict__ wc1, const float* __restrict__ bc1,
         const _Float16* __restrict__ pool, _Float16* __restrict__ rgb)
{
    __shared__ __align__(16) u32 smem[SMEM_W];
    const int tid   = threadIdx.x;            // 0..63 == lane
    const int pbase = blockIdx.x * 64;
    const int col   = tid & 31;
    const int hi    = tid >> 5;

    // hoisted ray ids
    int rid[2];
#pragma unroll
    for (int t = 0; t < 2; ++t) rid[t] = ray_id[pbase + 32*t + col];

    // ---- stage emb for own point (frags kc0/kc1 + w16 word) ----
    {
        const int pt = pbase + tid;
        const float x = coor[3*pt+0], y = coor[3*pt+1], z = coor[3*pt+2];
        u32 w_[17];
        w_[0] = pk(x, y); w_[1] = pk(z, 1.0f);   // slot3 = 1 -> bias rows
#pragma unroll
        for (int f = 0; f < 5; ++f) {
            const float fac = (float)(1 << f);
            float sx = __sinf(fac*x), cx = __cosf(fac*x);
            float sy = __sinf(fac*y), cy = __cosf(fac*y);
            float sz = __sinf(fac*z), cz = __cosf(fac*z);
            w_[2+3*f+0] = pk(sx,sy); w_[2+3*f+1] = pk(sz,cx); w_[2+3*f+2] = pk(cy,cz);
        }
#pragma unroll
        for (int fi = 0; fi < 4; ++fi)
            *(u32x4*)&smem[(fi*64 + tid)*4] =
                (u32x4){w_[4*fi], w_[4*fi+1], w_[4*fi+2], w_[4*fi+3]};
        smem[1024 + tid] = w_[16];
    }
    __syncthreads();

#define LDE(t, kc) __builtin_bit_cast(f16x8, *(const u32x4*)&smem[(((kc)*2 + hi)*64 + 32*(t) + col)*4])

    const float* bt = (const float*)(pool + BTAB_H);
    const f32x16 Z = zero16();

    f16x8 b[2][4];
    f32x16 bv[2];

    // kc=2 emb fragment: only slots 32,33 nonzero (hi=0 lanes)
    f16x8 E2[2];
#pragma unroll
    for (int t = 0; t < 2; ++t) {
        u32 w16v = smem[1024 + 32*t + col];
        u32x4 e2w = { hi == 0 ? w16v : 0u, 0u, 0u, 0u };
        E2[t] = __builtin_bit_cast(f16x8, e2w);
    }

    // ---- L0: kc0/kc1 from LDS, kc2 = E2; bias via emb slot3 ----
    {
        f16x8 W[2][3];
        loadWn<3,48>(W, pool + WB0T_OFF, col, hi);
#pragma unroll
        for (int t = 0; t < 2; ++t) {
            f16x8 e0 = LDE(t, 0), e1 = LDE(t, 1);
            f32x16 a0 = MFMA32(W[0][0], e0, Z);
            f32x16 a1 = MFMA32(W[1][0], e0, Z);
            a0 = MFMA32(W[0][1], e1, a0);
            a1 = MFMA32(W[1][1], e1, a1);
            a0 = MFMA32(W[0][2], E2[t], a0);
            a1 = MFMA32(W[1][2], E2[t], a1);
            d2b<true>(a0, b[t][0], b[t][1]);
            d2b<true>(a1, b[t][2], b[t][3]);
        }
    }

    {   // d1
        f16x8 W[2][4];
        loadWn<4,64>(W, pool + WB1T_OFF, col, hi);
        loadBV(bv, bt, 0, hi);
        dense2<true>(W, bv, b);
    }
    {   // d2
        f16x8 W[2][4];
        loadWn<4,64>(W, pool + WB2T_OFF, col, hi);
        loadBV(bv, bt, 1, hi);
        dense2<true>(W, bv, b);
    }

    // ---- skip: emb (kc0,kc1,E2; bias via slot3) + h2 (4 kc) ----
    {
        f16x8 We[2][3], Wh[2][4];
        loadWn<3,112>(We, pool + WA0T_OFF, col, hi);
        loadWn<4,112>(Wh, pool + WA0T_OFF + 48, col, hi);
#pragma unroll
        for (int t = 0; t < 2; ++t) {
            f16x8 e0 = LDE(t, 0), e1 = LDE(t, 1);
            f32x16 a0 = MFMA32(We[0][0], e0, Z);
            f32x16 a1 = MFMA32(We[1][0], e0, Z);
            a0 = MFMA32(We[0][1], e1, a0);
            a1 = MFMA32(We[1][1], e1, a1);
            a0 = MFMA32(We[0][2], E2[t], a0);
            a1 = MFMA32(We[1][2], E2[t], a1);
#pragma unroll
            for (int kc = 0; kc < 4; ++kc) {
                a0 = MFMA32(Wh[0][kc], b[t][kc], a0);
                a1 = MFMA32(Wh[1][kc], b[t][kc], a1);
            }
            d2b<true>(a0, b[t][0], b[t][1]);
            d2b<true>(a1, b[t][2], b[t][3]);
        }
    }

    {   // d3
        f16x8 W[2][4];
        loadWn<4,64>(W, pool + WA1T_OFF, col, hi);
        loadBV(bv, bt, 2, hi);
        dense2<true>(W, bv, b);
    }
    {   // d4
        f16x8 W[2][4];
        loadWn<4,64>(W, pool + WA2T_OFF, col, hi);
        loadBV(bv, bt, 3, hi);
        dense2<true>(W, bv, b);
    }

    // vemb gather (latency hides under lat layer)
    const _Float16* vtab = pool + VTAB_OFF;
    f16x8 VE[2][2];
#pragma unroll
    for (int t = 0; t < 2; ++t)
#pragma unroll
        for (int kc = 0; kc < 2; ++kc)
            VE[t][kc] = *(const f16x8*)(vtab + rid[t]*32 + kc*16 + hi*8);

    {   // latent (no relu)
        f16x8 W[2][4];
        loadWn<4,64>(W, pool + WLATT_OFF, col, hi);
        loadBV(bv, bt, 4, hi);
        dense2<false>(W, bv, b);
    }

    // ---- view: lat(4 kc) + vemb(2 kc, bias via vemb slot3); 32 of ----
    {
        f16x8 Wv[6];
#pragma unroll
        for (int kc = 0; kc < 6; ++kc)
            Wv[kc] = *(const f16x8*)(pool + WVIEWT_OFF + col*96 + kc*16 + hi*8);
#pragma unroll
        for (int t = 0; t < 2; ++t) {
            f32x16 a = MFMA32(Wv[0], b[t][0], Z);
#pragma unroll
            for (int kc = 1; kc < 4; ++kc) a = MFMA32(Wv[kc], b[t][kc], a);
            a = MFMA32(Wv[4], VE[t][0], a);
            a = MFMA32(Wv[5], VE[t][1], a);
            d2b<true>(a, b[t][0], b[t][1]);
        }
    }

    // ---- c0 (C-init bias) + c1 (16->3) + squash ----
    {
        f16x8 Wc[2];
#pragma unroll
        for (int kc = 0; kc < 2; ++kc)
            Wc[kc] = *(const f16x8*)(pool + WC0T_OFF + col*32 + kc*16 + hi*8);

        f32x16 C = zero16();
        {
            f32x4 c0a = *(const f32x4*)(bt + 320 + hi*8);
            f32x4 c0b = *(const f32x4*)(bt + 320 + hi*8 + 4);
#pragma unroll
            for (int s = 0; s < 4; ++s) { C[s] = c0a[s]; C[4+s] = c0b[s]; }
        }

        float wl[24];
        {
            f32x4 w0 = *(const f32x4*)(wc1 + 12*hi);
            f32x4 w1 = *(const f32x4*)(wc1 + 12*hi + 4);
            f32x4 w2 = *(const f32x4*)(wc1 + 12*hi + 8);
            f32x4 w3 = *(const f32x4*)(wc1 + 24 + 12*hi);
            f32x4 w4 = *(const f32x4*)(wc1 + 24 + 12*hi + 4);
            f32x4 w5 = *(const f32x4*)(wc1 + 24 + 12*hi + 8);
#pragma unroll
            for (int s = 0; s < 4; ++s) {
                wl[s]    = w0[s]; wl[4+s]  = w1[s]; wl[8+s]  = w2[s];
                wl[12+s] = w3[s]; wl[16+s] = w4[s]; wl[20+s] = w5[s];
            }
        }
        const float bo0 = bc1[0], bo1 = bc1[1], bo2 = bc1[2];

#pragma unroll
        for (int t = 0; t < 2; ++t) {
            f32x16 a = MFMA32(Wc[0], b[t][0], C);
            a = MFMA32(Wc[1], b[t][1], a);
            float hc[8];
#pragma unroll
            for (int i = 0; i < 8; ++i) hc[i] = fmaxf(a[i], 0.f);

            float r0 = 0.f, r1 = 0.f, r2 = 0.f;
#pragma unroll
            for (int q = 0; q < 4; ++q) {
                r0 = fmaf(hc[q], wl[3*q+0], fmaf(hc[4+q], wl[12+3*q+0], r0));
                r1 = fmaf(hc[q], wl[3*q+1], fmaf(hc[4+q], wl[12+3*q+1], r1));
                r2 = fmaf(hc[q], wl[3*q+2], fmaf(hc[4+q], wl[12+3*q+2], r2));
            }
            r0 += __shfl_xor(r0, 32);
            r1 += __shfl_xor(r1, 32);
            r2 += __shfl_xor(r2, 32);
            if (hi == 0) {
                const float K2 = 2.8853900817779268f;   // 2*log2(e)
                float e0 = exp2f(K2 * (r0 + bo0));
                float e1 = exp2f(K2 * (r1 + bo1));
                float e2 = exp2f(K2 * (r2 + bo2));
                float v0 = 1.f - __builtin_amdgcn_rcpf(e0 + 1.f);
                float v1 = 1.f - __builtin_amdgcn_rcpf(e1 + 1.f);
                float v2 = 1.f - __builtin_amdgcn_rcpf(e2 + 1.f);
                const int pt = pbase + 32*t + col;
                rgb[3*pt+0] = (_Float16)v0;
                rgb[3*pt+1] = (_Float16)v1;
                rgb[3*pt+2] = (_Float16)v2;
            }
        }
    }
#undef LDE
}

// ================= per-ray composite (one wave per ray, table-driven) =======
extern "C" __global__ void __launch_bounds__(256)
composite(const float* __restrict__ raw_density,
          const int*   __restrict__ rtab,
          const _Float16* __restrict__ rgb,
          float*       __restrict__ out)
{
    const int lane = threadIdx.x & 63;
    const int ray  = blockIdx.x * 4 + (threadIdx.x >> 6);

    const int start = rtab[ray];
    const int end   = rtab[ray + 1];

    float carry = 0.0f, a0 = 0.0f, a1 = 0.0f, a2 = 0.0f;

    for (int base = start; base < end; base += 64) {
        const int  idx   = base + lane;
        const bool valid = idx < end;

        float lt = 0.0f, alpha = 0.0f;
        if (valid) {
            const float xx  = raw_density[idx] + ACT_SHIFT_F;
            const float sig = fmaxf(xx, 0.0f) + log1pf(expf(-fabsf(xx)));  // softplus
            lt    = -sig * INTERVAL_F;
            alpha = 1.0f - expf(lt);
        }

        float incl = lt;
#pragma unroll
        for (int d = 1; d < 64; d <<= 1) {
            const float n = __shfl_up(incl, d);
            if (lane >= d) incl += n;
        }

        const float T = expf(carry + (incl - lt));
        if (valid) {
            const float w = T * alpha;
            a0 = fmaf(w, (float)rgb[3*idx+0], a0);
            a1 = fmaf(w, (float)rgb[3*idx+1], a1);
            a2 = fmaf(w, (float)rgb[3*idx+2], a2);
        }
        carry += __shfl(incl, 63);
    }

#pragma unroll
    for (int d = 32; d > 0; d >>= 1) {
        a0 += __shfl_xor(a0, d);
        a1 += __shfl_xor(a1, d);
        a2 += __shfl_xor(a2, d);
    }

    if (lane == 0) {
        const float ainv = expf(carry);
        out[3*ray+0] = a0 + ainv;
        out[3*ray+1] = a1 + ainv;
        out[3*ray+2] = a2 + ainv;
    }
}

// ================= launch ===================================================
extern "C" void kernel_launch(void* const* d_in, const int* in_sizes, int n_in,
                              void* d_out, int out_size, void* d_ws, size_t ws_size,
                              hipStream_t stream) {
    const float* coor        = (const float*)d_in[0];
    const float* view        = (const float*)d_in[1];
    const float* raw_density = (const float*)d_in[2];
    const int*   ray_id      = (const int*)  d_in[3];
    const float* wb0  = (const float*)d_in[4];  const float* bb0  = (const float*)d_in[5];
    const float* wb1  = (const float*)d_in[6];  const float* bb1  = (const float*)d_in[7];
    const float* wb2  = (const float*)d_in[8];  const float* bb2  = (const float*)d_in[9];
    const float* wa0  = (const float*)d_in[10]; const float* ba0  = (const float*)d_in[11];
    const float* wa1  = (const float*)d_in[12]; const float* ba1  = (const float*)d_in[13];
    const float* wa2  = (const float*)d_in[14]; const float* ba2  = (const float*)d_in[15];
    const float* wlat = (const float*)d_in[16]; const float* blat = (const float*)d_in[17];
    const float* wvw  = (const float*)d_in[18]; const float* bvw  = (const float*)d_in[19];
    const float* wc0  = (const float*)d_in[20]; const float* bc0  = (const float*)d_in[21];
    const float* wc1  = (const float*)d_in[22]; const float* bc1  = (const float*)d_in[23];

    _Float16* rgb  = (_Float16*)d_ws;                                   // P*3 f16 = 3.15 MB
    _Float16* pool = (_Float16*)((char*)d_ws + (size_t)NPTS * 3 * 2);
    const int* rtab = (const int*)(pool + RAYTAB_H);

    prep_weights<<<(PREP_TOTAL + 255) / 256, 256, 0, stream>>>(
        wb0, bb0, wb1, bb1, wb2, bb2, wa0, ba0, wa1, ba1, wa2, ba2,
        wlat, blat, wvw, bvw, wc0, bc0, view, ray_id, pool);

    mlp_mfma<<<NPTS / 64, 64, 0, stream>>>(
        coor, ray_id, wc1, bc1, pool, rgb);

    composite<<<NRAYS / 4, 256, 0, stream>>>(raw_density, rtab, rgb, (float*)d_out);
}

// Round 11
// 52.708 us; speedup vs baseline: 1.4345x; 1.4345x over previous
//
#include <hip/hip_runtime.h>
#include <math.h>

#define NPTS  524288
#define NRAYS 4096
#define ACT_SHIFT_F (-2.1972245773362196f)   // log(1/(1-0.1) - 1)
#define INTERVAL_F  0.5f

typedef _Float16 f16x8  __attribute__((ext_vector_type(8)));
typedef __fp16   fp16x2 __attribute__((ext_vector_type(2)));
typedef float    f32x4  __attribute__((ext_vector_type(4)));
typedef float    f32x16 __attribute__((ext_vector_type(16)));
typedef int      i32x2  __attribute__((ext_vector_type(2)));
typedef unsigned u32;
typedef unsigned u32x2  __attribute__((ext_vector_type(2)));
typedef unsigned u32x4  __attribute__((ext_vector_type(4)));

#define MFMA32(a,b,c) __builtin_amdgcn_mfma_f32_32x32x16_f16((a),(b),(c),0,0,0)

// ---- padded pool (halves). LDS regions use S = KPAD+4 (bank-friendly b64):
// emb slots: [x,y,z,1,(s,s,s,c,c,c)*5] (34 used); slot3=1 drives bias rows of
// wb0/wa0 (row k=3). vemb slot3=1 drives wview row 67.
#define WB0_H    0       // 64 x 52
#define WB1_H    3328    // 64 x 68
#define WB2_H    7680    // 64 x 68
#define WA0_H    12032   // 64 x 116 (k<48 emb block incl bias row3; 48..111 h2)
#define WA1_H    19456   // 64 x 68
#define WA2_H    23808   // 64 x 68
#define WLAT_H   28160   // 64 x 68
#define WLDS_H   32512   // end of LDS-resident prefix (= 16256 u32 = 65024 B)
#define WVIEW_H  32512   // 32 x 96 (global, unpadded)
#define WC0_H    35584   // 32 x 32 (global)
#define WEND_H   36608
#define BTAB_H   36608   // 384 f32 (768 halves), C-frag order
#define VTAB_H   37376   // 4096 rays x 32 halves
#define RAYTAB_H 168448  // (NRAYS+1) ints
#define PREP_W    36608
#define PREP_BT   (PREP_W + 384)
#define PREP_IDS  (PREP_BT + NRAYS)
#define PREP_TOTAL (PREP_IDS + NPTS)

// u32 strides / offsets for LDS weight reads
#define S2_WB0 26
#define S2_D   34
#define S2_WA0 58
#define U_WB0  0
#define U_WB1  1664
#define U_WB2  3840
#define U_WA0  6016
#define U_WA1  9728
#define U_WA2  11904
#define U_WLAT 14080
#define LDS_U32 16256

// ================= helpers ==================================================
__device__ __forceinline__ u32 pk(float a, float b) {
    fp16x2 h = __builtin_amdgcn_cvt_pkrtz(a, b);
    return __builtin_bit_cast(u32, h);
}

__device__ __forceinline__ void plswap(u32 &x, u32 &y) {
    i32x2 r = __builtin_amdgcn_permlane32_swap((int)x, (int)y, false, false);
    x = (u32)r[0]; y = (u32)r[1];
}

__device__ __forceinline__ f32x16 zero16() {
    f32x16 z;
#pragma unroll
    for (int i = 0; i < 16; ++i) z[i] = 0.f;
    return z;
}

template<bool RELU>
__device__ __forceinline__ f16x8 reluq(f16x8 v) {
    if (RELU) {
        f16x8 z = {};
        return __builtin_elementwise_max(v, z);   // v_pk_max_f16 x4
    }
    return v;
}

// D(32x32 tile) -> two B k-chunk fragments of next layer (HW-verified r5-r10)
template<bool RELU>
__device__ __forceinline__ void d2b(f32x16 a, f16x8 &blo, f16x8 &bhi) {
    u32 p0 = pk(a[0],a[1]),   p1 = pk(a[2],a[3]);
    u32 p2 = pk(a[4],a[5]),   p3 = pk(a[6],a[7]);
    plswap(p0, p2); plswap(p1, p3);
    u32x4 lo = {p0, p1, p2, p3};
    blo = reluq<RELU>(__builtin_bit_cast(f16x8, lo));
    u32 p4 = pk(a[8],a[9]),   p5 = pk(a[10],a[11]);
    u32 p6 = pk(a[12],a[13]), p7 = pk(a[14],a[15]);
    plswap(p4, p6); plswap(p5, p7);
    u32x4 hw = {p4, p5, p6, p7};
    bhi = reluq<RELU>(__builtin_bit_cast(f16x8, hw));
}

// W fragment from LDS: two ds_read_b64 (8B-aligned; stride keeps banks spread)
__device__ __forceinline__ f16x8 ldw(const u32* __restrict__ sw, int u) {
    u32x2 a = *(const u32x2*)(sw + u);
    u32x2 b = *(const u32x2*)(sw + u + 2);
    u32x4 r = {a[0], a[1], b[0], b[1]};
    return __builtin_bit_cast(f16x8, r);
}

// ================= prep: padded weights + btab + vemb + ray-start ===========
extern "C" __global__ void __launch_bounds__(256)
prep_weights(const float* __restrict__ wb0, const float* __restrict__ bb0,
             const float* __restrict__ wb1, const float* __restrict__ bb1,
             const float* __restrict__ wb2, const float* __restrict__ bb2,
             const float* __restrict__ wa0, const float* __restrict__ ba0,
             const float* __restrict__ wa1, const float* __restrict__ ba1,
             const float* __restrict__ wa2, const float* __restrict__ ba2,
             const float* __restrict__ wlat, const float* __restrict__ blat,
             const float* __restrict__ wview, const float* __restrict__ bview,
             const float* __restrict__ wc0, const float* __restrict__ bc0,
             const float* __restrict__ view, const int* __restrict__ ray_id,
             _Float16* __restrict__ pool)
{
    const int id = blockIdx.x * 256 + threadIdx.x;
    if (id >= PREP_TOTAL) return;

    if (id < PREP_W) {
        int r = id; float v = 0.f;
        if (r < 3328) {                                   // WB0 64x52
            int n = r / 52, k = r % 52;
            if (k < 3) v = wb0[k*64+n]; else if (k == 3) v = bb0[n];
            else if (k < 34) v = wb0[(k-1)*64+n];
        } else if (r < 7680) { r -= 3328;                 // WB1 64x68
            int n = r / 68, k = r % 68; if (k < 64) v = wb1[k*64+n];
        } else if (r < 12032) { r -= 7680;                // WB2
            int n = r / 68, k = r % 68; if (k < 64) v = wb2[k*64+n];
        } else if (r < 19456) { r -= 12032;               // WA0 64x116
            int n = r / 116, k = r % 116;
            if (k < 3) v = wa0[k*64+n]; else if (k == 3) v = ba0[n];
            else if (k < 34) v = wa0[(k-1)*64+n];
            else if (k >= 48 && k < 112) v = wa0[(k-15)*64+n];   // 33+(k-48)
        } else if (r < 23808) { r -= 19456;               // WA1
            int n = r / 68, k = r % 68; if (k < 64) v = wa1[k*64+n];
        } else if (r < 28160) { r -= 23808;               // WA2
            int n = r / 68, k = r % 68; if (k < 64) v = wa2[k*64+n];
        } else if (r < 32512) { r -= 28160;               // WLAT
            int n = r / 68, k = r % 68; if (k < 64) v = wlat[k*64+n];
        } else if (r < 35584) { r -= 32512;               // WVIEW 32x96
            int n = r / 96, k = r % 96;
            if (k < 64) v = wview[k*32+n];
            else { int s = k - 64;
                   if (s < 3) v = wview[(64+s)*32+n];
                   else if (s == 3) v = bview[n];
                   else if (s < 22) v = wview[(63+s)*32+n]; }
        } else { r -= 35584;                              // WC0 32x32
            int n = r >> 5, k = r & 31;
            if (n < 16) v = wc0[k*16+n];
        }
        pool[id] = (_Float16)v;
        return;
    }

    if (id < PREP_BT) {                       // bias table f32, C-frag order
        float* bt = (float*)(pool + BTAB_H);
        const int e = id - PREP_W; float v = 0.f;
        if (e < 320) {
            int l = e >> 6, rem = e & 63;
            int mt = rem >> 5, hi2 = (rem >> 4) & 1, q = rem & 15;
            int row = (q & 3) + 8*(q >> 2) + 4*hi2 + 32*mt;
            const float* src[5] = { bb1, bb2, ba1, ba2, blat };
            v = src[l][row];
        } else if (e < 336) {
            int t = e - 320, hi2 = t >> 3, q = t & 7;
            int row = (q & 3) + 8*(q >> 2) + 4*hi2;
            v = bc0[row];
        }
        bt[e] = v;
        return;
    }

    if (id < PREP_IDS) {
        // per-ray vemb row: [vx,vy,vz,1, (s,s,s,c,c,c)*3, 0-pad..31]
        const int ray = id - PREP_BT;
        const float vx = view[3*ray+0], vy = view[3*ray+1], vz = view[3*ray+2];
        u32 w_[16];
        w_[0] = pk(vx, vy); w_[1] = pk(vz, 1.0f);   // slot3=1 -> bias row 67
#pragma unroll
        for (int f = 0; f < 3; ++f) {
            const float fac = (float)(1 << f);
            float sx = __sinf(fac*vx), cx = __cosf(fac*vx);
            float sy = __sinf(fac*vy), cy = __cosf(fac*vy);
            float sz = __sinf(fac*vz), cz = __cosf(fac*vz);
            w_[2+3*f+0] = pk(sx,sy); w_[2+3*f+1] = pk(sz,cx); w_[2+3*f+2] = pk(cy,cz);
        }
#pragma unroll
        for (int i = 11; i < 16; ++i) w_[i] = 0u;
        u32* dst = (u32*)(pool + VTAB_H) + ray * 16;
#pragma unroll
        for (int i = 0; i < 4; ++i)
            ((u32x4*)dst)[i] = (u32x4){w_[4*i], w_[4*i+1], w_[4*i+2], w_[4*i+3]};
        return;
    }

    // ray-start table from sorted ray_id
    {
        const int p = id - PREP_IDS;
        int* tab = (int*)(pool + RAYTAB_H);
        const int cur  = ray_id[p];
        const int prev = (p == 0) ? -1 : ray_id[p-1];
        for (int r = prev + 1; r <= cur; ++r) tab[r] = p;
        if (p == NPTS - 1)
            for (int r = cur + 1; r <= NRAYS; ++r) tab[r] = NPTS;
    }
}

// ================= dense 64->64 from LDS weights ============================
__device__ __forceinline__ void loadBV(f32x16 (&bv)[2], const float* __restrict__ bt,
                                       int l, int hi) {
#pragma unroll
    for (int mt = 0; mt < 2; ++mt) {
        const float* p = bt + l*64 + (mt*2 + hi)*16;
#pragma unroll
        for (int i = 0; i < 4; ++i) {
            f32x4 v = *(const f32x4*)(p + 4*i);
#pragma unroll
            for (int s = 0; s < 4; ++s) bv[mt][4*i + s] = v[s];
        }
    }
}

template<bool RELU>
__device__ __forceinline__ void denseL(const u32* __restrict__ sw, int base,
                                       const f32x16 (&bv)[2], f16x8 (&b)[4][4],
                                       int col, int hi) {
    f16x8 W[2][4];
#pragma unroll
    for (int mt = 0; mt < 2; ++mt)
#pragma unroll
        for (int kc = 0; kc < 4; ++kc)
            W[mt][kc] = ldw(sw, base + (mt*32 + col)*S2_D + kc*8 + hi*4);
#pragma unroll
    for (int t = 0; t < 4; ++t) {
        f32x16 a0 = MFMA32(W[0][0], b[t][0], bv[0]);
        f32x16 a1 = MFMA32(W[1][0], b[t][0], bv[1]);
#pragma unroll
        for (int kc = 1; kc < 4; ++kc) {
            a0 = MFMA32(W[0][kc], b[t][kc], a0);
            a1 = MFMA32(W[1][kc], b[t][kc], a1);
        }
        d2b<RELU>(a0, b[t][0], b[t][1]);
        d2b<RELU>(a1, b[t][2], b[t][3]);
    }
}

// ================= fused MLP: 4-wave block, 128 pts/wave ====================
extern "C" __global__ void __launch_bounds__(256, 2)
mlp_mfma(const float* __restrict__ coor, const int* __restrict__ ray_id,
         const float* __restrict__ wc1, const float* __restrict__ bc1,
         const _Float16* __restrict__ pool, _Float16* __restrict__ rgb)
{
    __shared__ __align__(16) u32 sw[LDS_U32];   // 65,024 B
    const int tid  = threadIdx.x;
    const int lane = tid & 63;
    const int wv   = tid >> 6;
    const int col  = lane & 31;
    const int hi   = lane >> 5;
    const int wbase = blockIdx.x * 512 + wv * 128;

    // ---- cooperative weight staging into LDS ----
    {
        const u32x4* pw = (const u32x4*)pool;
        u32x4* dw = (u32x4*)sw;
#pragma unroll 4
        for (int i = tid; i < LDS_U32/4; i += 256) dw[i] = pw[i];
    }

    int rid[4];
#pragma unroll
    for (int t = 0; t < 4; ++t) rid[t] = ray_id[wbase + 32*t + col];

    // ---- emb B-fragments in-register via permlane32_swap ----
    f16x8 E[4][3];
#pragma unroll
    for (int s = 0; s < 2; ++s) {
        const int pt = wbase + s*64 + lane;
        const float x = coor[3*pt+0], y = coor[3*pt+1], z = coor[3*pt+2];
        u32 w_[17];
        w_[0] = pk(x, y); w_[1] = pk(z, 1.0f);   // slot3=1 -> bias rows
#pragma unroll
        for (int f = 0; f < 5; ++f) {
            const float fac = (float)(1 << f);
            float sx = __sinf(fac*x), cx = __cosf(fac*x);
            float sy = __sinf(fac*y), cy = __cosf(fac*y);
            float sz = __sinf(fac*z), cz = __cosf(fac*z);
            w_[2+3*f+0] = pk(sx,sy); w_[2+3*f+1] = pk(sz,cx); w_[2+3*f+2] = pk(cy,cz);
        }
        // kc 0/1: swap lo/hi word quads -> frag for tile 2s (x') and 2s+1 (y')
#pragma unroll
        for (int kc = 0; kc < 2; ++kc) {
            u32 xw[4], yw[4];
#pragma unroll
            for (int i = 0; i < 4; ++i) {
                xw[i] = w_[kc*8 + i]; yw[i] = w_[kc*8 + 4 + i];
                plswap(xw[i], yw[i]);
            }
            u32x4 lo = {xw[0], xw[1], xw[2], xw[3]};
            u32x4 hw = {yw[0], yw[1], yw[2], yw[3]};
            E[2*s  ][kc] = __builtin_bit_cast(f16x8, lo);
            E[2*s+1][kc] = __builtin_bit_cast(f16x8, hw);
        }
        // kc 2: slots 32,33 word only
        u32 X = w_[16], Y = 0u;
        plswap(X, Y);
        u32x4 e2a = {X, 0u, 0u, 0u}, e2b = {Y, 0u, 0u, 0u};
        E[2*s  ][2] = __builtin_bit_cast(f16x8, e2a);
        E[2*s+1][2] = __builtin_bit_cast(f16x8, e2b);
    }
    __syncthreads();   // weights staged

    const float* bt = (const float*)(pool + BTAB_H);
    const f32x16 Z = zero16();

    f16x8 b[4][4];
    f32x16 bv[2];

    // ---- L0: 3 kc emb frags; bias via slot3 ----
    {
        f16x8 W[2][3];
#pragma unroll
        for (int mt = 0; mt < 2; ++mt)
#pragma unroll
            for (int kc = 0; kc < 3; ++kc)
                W[mt][kc] = ldw(sw, U_WB0 + (mt*32 + col)*S2_WB0 + kc*8 + hi*4);
#pragma unroll
        for (int t = 0; t < 4; ++t) {
            f32x16 a0 = MFMA32(W[0][0], E[t][0], Z);
            f32x16 a1 = MFMA32(W[1][0], E[t][0], Z);
            a0 = MFMA32(W[0][1], E[t][1], a0);
            a1 = MFMA32(W[1][1], E[t][1], a1);
            a0 = MFMA32(W[0][2], E[t][2], a0);
            a1 = MFMA32(W[1][2], E[t][2], a1);
            d2b<true>(a0, b[t][0], b[t][1]);
            d2b<true>(a1, b[t][2], b[t][3]);
        }
    }

    loadBV(bv, bt, 0, hi);
    denseL<true>(sw, U_WB1, bv, b, col, hi);   // d1
    loadBV(bv, bt, 1, hi);
    denseL<true>(sw, U_WB2, bv, b, col, hi);   // d2

    // ---- skip: emb (3 kc, bias via slot3) + h2 (4 kc); no bv needed ----
    {
        f16x8 We[2][3], Wh[2][4];
#pragma unroll
        for (int mt = 0; mt < 2; ++mt) {
#pragma unroll
            for (int kc = 0; kc < 3; ++kc)
                We[mt][kc] = ldw(sw, U_WA0 + (mt*32 + col)*S2_WA0 + kc*8 + hi*4);
#pragma unroll
            for (int kc = 0; kc < 4; ++kc)
                Wh[mt][kc] = ldw(sw, U_WA0 + (mt*32 + col)*S2_WA0 + 24 + kc*8 + hi*4);
        }
#pragma unroll
        for (int t = 0; t < 4; ++t) {
            f32x16 a0 = MFMA32(We[0][0], E[t][0], Z);
            f32x16 a1 = MFMA32(We[1][0], E[t][0], Z);
            a0 = MFMA32(We[0][1], E[t][1], a0);
            a1 = MFMA32(We[1][1], E[t][1], a1);
            a0 = MFMA32(We[0][2], E[t][2], a0);
            a1 = MFMA32(We[1][2], E[t][2], a1);
#pragma unroll
            for (int kc = 0; kc < 4; ++kc) {
                a0 = MFMA32(Wh[0][kc], b[t][kc], a0);
                a1 = MFMA32(Wh[1][kc], b[t][kc], a1);
            }
            d2b<true>(a0, b[t][0], b[t][1]);
            d2b<true>(a1, b[t][2], b[t][3]);
        }
    }

    loadBV(bv, bt, 2, hi);
    denseL<true>(sw, U_WA1, bv, b, col, hi);   // d3
    loadBV(bv, bt, 3, hi);
    denseL<true>(sw, U_WA2, bv, b, col, hi);   // d4

    // vemb gather (latency hides under lat layer)
    const _Float16* vtab = pool + VTAB_H;
    f16x8 VE[4][2];
#pragma unroll
    for (int t = 0; t < 4; ++t)
#pragma unroll
        for (int kc = 0; kc < 2; ++kc)
            VE[t][kc] = *(const f16x8*)(vtab + rid[t]*32 + kc*16 + hi*8);

    loadBV(bv, bt, 4, hi);
    denseL<false>(sw, U_WLAT, bv, b, col, hi); // latent (no relu)

    // ---- view: lat(4 kc) + vemb(2 kc, bias via vemb slot3); 32 of (global W)
    {
        f16x8 Wv[6];
#pragma unroll
        for (int kc = 0; kc < 6; ++kc)
            Wv[kc] = *(const f16x8*)(pool + WVIEW_H + col*96 + kc*16 + hi*8);
#pragma unroll
        for (int t = 0; t < 4; ++t) {
            f32x16 a = MFMA32(Wv[0], b[t][0], Z);
#pragma unroll
            for (int kc = 1; kc < 4; ++kc) a = MFMA32(Wv[kc], b[t][kc], a);
            a = MFMA32(Wv[4], VE[t][0], a);
            a = MFMA32(Wv[5], VE[t][1], a);
            d2b<true>(a, b[t][0], b[t][1]);
        }
    }

    // ---- c0 (C-init bias) + c1 (16->3) + squash ----
    {
        f16x8 Wc[2];
#pragma unroll
        for (int kc = 0; kc < 2; ++kc)
            Wc[kc] = *(const f16x8*)(pool + WC0_H + col*32 + kc*16 + hi*8);

        f32x16 C = zero16();
        {
            f32x4 c0a = *(const f32x4*)(bt + 320 + hi*8);
            f32x4 c0b = *(const f32x4*)(bt + 320 + hi*8 + 4);
#pragma unroll
            for (int s = 0; s < 4; ++s) { C[s] = c0a[s]; C[4+s] = c0b[s]; }
        }

        float wl[24];
        {
            f32x4 w0 = *(const f32x4*)(wc1 + 12*hi);
            f32x4 w1 = *(const f32x4*)(wc1 + 12*hi + 4);
            f32x4 w2 = *(const f32x4*)(wc1 + 12*hi + 8);
            f32x4 w3 = *(const f32x4*)(wc1 + 24 + 12*hi);
            f32x4 w4 = *(const f32x4*)(wc1 + 24 + 12*hi + 4);
            f32x4 w5 = *(const f32x4*)(wc1 + 24 + 12*hi + 8);
#pragma unroll
            for (int s = 0; s < 4; ++s) {
                wl[s]    = w0[s]; wl[4+s]  = w1[s]; wl[8+s]  = w2[s];
                wl[12+s] = w3[s]; wl[16+s] = w4[s]; wl[20+s] = w5[s];
            }
        }
        const float bo0 = bc1[0], bo1 = bc1[1], bo2 = bc1[2];

#pragma unroll
        for (int t = 0; t < 4; ++t) {
            f32x16 a = MFMA32(Wc[0], b[t][0], C);
            a = MFMA32(Wc[1], b[t][1], a);
            float hc[8];
#pragma unroll
            for (int i = 0; i < 8; ++i) hc[i] = fmaxf(a[i], 0.f);

            float r0 = 0.f, r1 = 0.f, r2 = 0.f;
#pragma unroll
            for (int q = 0; q < 4; ++q) {
                r0 = fmaf(hc[q], wl[3*q+0], fmaf(hc[4+q], wl[12+3*q+0], r0));
                r1 = fmaf(hc[q], wl[3*q+1], fmaf(hc[4+q], wl[12+3*q+1], r1));
                r2 = fmaf(hc[q], wl[3*q+2], fmaf(hc[4+q], wl[12+3*q+2], r2));
            }
            r0 += __shfl_xor(r0, 32);
            r1 += __shfl_xor(r1, 32);
            r2 += __shfl_xor(r2, 32);
            if (hi == 0) {
                const float K2 = 2.8853900817779268f;   // 2*log2(e)
                float e0 = exp2f(K2 * (r0 + bo0));
                float e1 = exp2f(K2 * (r1 + bo1));
                float e2 = exp2f(K2 * (r2 + bo2));
                float v0 = 1.f - __builtin_amdgcn_rcpf(e0 + 1.f);
                float v1 = 1.f - __builtin_amdgcn_rcpf(e1 + 1.f);
                float v2 = 1.f - __builtin_amdgcn_rcpf(e2 + 1.f);
                const int pt = wbase + 32*t + col;
                rgb[3*pt+0] = (_Float16)v0;
                rgb[3*pt+1] = (_Float16)v1;
                rgb[3*pt+2] = (_Float16)v2;
            }
        }
    }
}

// ================= per-ray composite (one wave per ray, table-driven) =======
extern "C" __global__ void __launch_bounds__(256)
composite(const float* __restrict__ raw_density,
          const int*   __restrict__ rtab,
          const _Float16* __restrict__ rgb,
          float*       __restrict__ out)
{
    const int lane = threadIdx.x & 63;
    const int ray  = blockIdx.x * 4 + (threadIdx.x >> 6);

    const int start = rtab[ray];
    const int end   = rtab[ray + 1];

    float carry = 0.0f, a0 = 0.0f, a1 = 0.0f, a2 = 0.0f;

    for (int base = start; base < end; base += 64) {
        const int  idx   = base + lane;
        const bool valid = idx < end;

        float lt = 0.0f, alpha = 0.0f;
        if (valid) {
            const float xx  = raw_density[idx] + ACT_SHIFT_F;
            const float sig = fmaxf(xx, 0.0f) + log1pf(expf(-fabsf(xx)));  // softplus
            lt    = -sig * INTERVAL_F;
            alpha = 1.0f - expf(lt);
        }

        float incl = lt;
#pragma unroll
        for (int d = 1; d < 64; d <<= 1) {
            const float n = __shfl_up(incl, d);
            if (lane >= d) incl += n;
        }

        const float T = expf(carry + (incl - lt));
        if (valid) {
            const float w = T * alpha;
            a0 = fmaf(w, (float)rgb[3*idx+0], a0);
            a1 = fmaf(w, (float)rgb[3*idx+1], a1);
            a2 = fmaf(w, (float)rgb[3*idx+2], a2);
        }
        carry += __shfl(incl, 63);
    }

#pragma unroll
    for (int d = 32; d > 0; d >>= 1) {
        a0 += __shfl_xor(a0, d);
        a1 += __shfl_xor(a1, d);
        a2 += __shfl_xor(a2, d);
    }

    if (lane == 0) {
        const float ainv = expf(carry);
        out[3*ray+0] = a0 + ainv;
        out[3*ray+1] = a1 + ainv;
        out[3*ray+2] = a2 + ainv;
    }
}

// ================= launch ===================================================
extern "C" void kernel_launch(void* const* d_in, const int* in_sizes, int n_in,
                              void* d_out, int out_size, void* d_ws, size_t ws_size,
                              hipStream_t stream) {
    const float* coor        = (const float*)d_in[0];
    const float* view        = (const float*)d_in[1];
    const float* raw_density = (const float*)d_in[2];
    const int*   ray_id      = (const int*)  d_in[3];
    const float* wb0  = (const float*)d_in[4];  const float* bb0  = (const float*)d_in[5];
    const float* wb1  = (const float*)d_in[6];  const float* bb1  = (const float*)d_in[7];
    const float* wb2  = (const float*)d_in[8];  const float* bb2  = (const float*)d_in[9];
    const float* wa0  = (const float*)d_in[10]; const float* ba0  = (const float*)d_in[11];
    const float* wa1  = (const float*)d_in[12]; const float* ba1  = (const float*)d_in[13];
    const float* wa2  = (const float*)d_in[14]; const float* ba2  = (const float*)d_in[15];
    const float* wlat = (const float*)d_in[16]; const float* blat = (const float*)d_in[17];
    const float* wvw  = (const float*)d_in[18]; const float* bvw  = (const float*)d_in[19];
    const float* wc0  = (const float*)d_in[20]; const float* bc0  = (const float*)d_in[21];
    const float* wc1  = (const float*)d_in[22]; const float* bc1  = (const float*)d_in[23];

    _Float16* rgb  = (_Float16*)d_ws;                                   // P*3 f16 = 3.15 MB
    _Float16* pool = (_Float16*)((char*)d_ws + (size_t)NPTS * 3 * 2);
    const int* rtab = (const int*)(pool + RAYTAB_H);

    prep_weights<<<(PREP_TOTAL + 255) / 256, 256, 0, stream>>>(
        wb0, bb0, wb1, bb1, wb2, bb2, wa0, ba0, wa1, ba1, wa2, ba2,
        wlat, blat, wvw, bvw, wc0, bc0, view, ray_id, pool);

    mlp_mfma<<<NPTS / 512, 256, 0, stream>>>(
        coor, ray_id, wc1, bc1, pool, rgb);

    composite<<<NRAYS / 4, 256, 0, stream>>>(raw_density, rtab, rgb, (float*)d_out);
}

// Round 12
// 52.060 us; speedup vs baseline: 1.4524x; 1.0124x over previous
//
#include <hip/hip_runtime.h>
#include <math.h>

#define NPTS  524288
#define NRAYS 4096
#define ACT_SHIFT_F (-2.1972245773362196f)   // log(1/(1-0.1) - 1)
#define INTERVAL_F  0.5f

typedef _Float16 f16x8  __attribute__((ext_vector_type(8)));
typedef __fp16   fp16x2 __attribute__((ext_vector_type(2)));
typedef float    f32x4  __attribute__((ext_vector_type(4)));
typedef float    f32x16 __attribute__((ext_vector_type(16)));
typedef int      i32x2  __attribute__((ext_vector_type(2)));
typedef unsigned u32;
typedef unsigned u32x2  __attribute__((ext_vector_type(2)));
typedef unsigned u32x4  __attribute__((ext_vector_type(4)));

#define MFMA32(a,b,c) __builtin_amdgcn_mfma_f32_32x32x16_f16((a),(b),(c),0,0,0)

// ---- padded pool (halves). LDS regions use S = KPAD+4 (bank-friendly b64):
// emb slots: [x,y,z,1,(s,s,s,c,c,c)*5] (34 used); slot3=1 drives bias rows of
// wb0/wa0 (row k=3). vemb slot3=1 drives wview row 67.
#define WB0_H    0       // 64 x 52
#define WB1_H    3328    // 64 x 68
#define WB2_H    7680    // 64 x 68
#define WA0_H    12032   // 64 x 116 (k<48 emb block incl bias row3; 48..111 h2)
#define WA1_H    19456   // 64 x 68
#define WA2_H    23808   // 64 x 68
#define WLAT_H   28160   // 64 x 68
#define WLDS_H   32512   // end of LDS-resident prefix (= 16256 u32 = 65024 B)
#define WVIEW_H  32512   // 32 x 96 (global, unpadded)
#define WC0_H    35584   // 32 x 32 (global)
#define WEND_H   36608
#define BTAB_H   36608   // 384 f32 (768 halves), C-frag order
#define VTAB_H   37376   // 4096 rays x 32 halves
#define RAYTAB_H 168448  // (NRAYS+1) ints
#define PREP_W    36608
#define PREP_BT   (PREP_W + 384)
#define PREP_IDS  (PREP_BT + NRAYS)
#define PREP_TOTAL (PREP_IDS + NPTS)

// u32 strides / offsets for LDS weight reads
#define S2_WB0 26
#define S2_D   34
#define S2_WA0 58
#define U_WB0  0
#define U_WB1  1664
#define U_WB2  3840
#define U_WA0  6016
#define U_WA1  9728
#define U_WA2  11904
#define U_WLAT 14080
#define LDS_U32 16256

// ================= helpers ==================================================
__device__ __forceinline__ u32 pk(float a, float b) {
    fp16x2 h = __builtin_amdgcn_cvt_pkrtz(a, b);
    return __builtin_bit_cast(u32, h);
}

__device__ __forceinline__ void plswap(u32 &x, u32 &y) {
    i32x2 r = __builtin_amdgcn_permlane32_swap((int)x, (int)y, false, false);
    x = (u32)r[0]; y = (u32)r[1];
}

__device__ __forceinline__ f32x16 zero16() {
    f32x16 z;
#pragma unroll
    for (int i = 0; i < 16; ++i) z[i] = 0.f;
    return z;
}

template<bool RELU>
__device__ __forceinline__ f16x8 reluq(f16x8 v) {
    if (RELU) {
        f16x8 z = {};
        return __builtin_elementwise_max(v, z);   // v_pk_max_f16 x4
    }
    return v;
}

// D(32x32 tile) -> two B k-chunk fragments of next layer (HW-verified r5-r11)
template<bool RELU>
__device__ __forceinline__ void d2b(f32x16 a, f16x8 &blo, f16x8 &bhi) {
    u32 p0 = pk(a[0],a[1]),   p1 = pk(a[2],a[3]);
    u32 p2 = pk(a[4],a[5]),   p3 = pk(a[6],a[7]);
    plswap(p0, p2); plswap(p1, p3);
    u32x4 lo = {p0, p1, p2, p3};
    blo = reluq<RELU>(__builtin_bit_cast(f16x8, lo));
    u32 p4 = pk(a[8],a[9]),   p5 = pk(a[10],a[11]);
    u32 p6 = pk(a[12],a[13]), p7 = pk(a[14],a[15]);
    plswap(p4, p6); plswap(p5, p7);
    u32x4 hw = {p4, p5, p6, p7};
    bhi = reluq<RELU>(__builtin_bit_cast(f16x8, hw));
}

// W fragment from LDS: two ds_read_b64
__device__ __forceinline__ f16x8 ldw(const u32* __restrict__ sw, int u) {
    u32x2 a = *(const u32x2*)(sw + u);
    u32x2 b = *(const u32x2*)(sw + u + 2);
    u32x4 r = {a[0], a[1], b[0], b[1]};
    return __builtin_bit_cast(f16x8, r);
}

// ================= prep: padded weights + btab + vemb + ray-start ===========
extern "C" __global__ void __launch_bounds__(256)
prep_weights(const float* __restrict__ wb0, const float* __restrict__ bb0,
             const float* __restrict__ wb1, const float* __restrict__ bb1,
             const float* __restrict__ wb2, const float* __restrict__ bb2,
             const float* __restrict__ wa0, const float* __restrict__ ba0,
             const float* __restrict__ wa1, const float* __restrict__ ba1,
             const float* __restrict__ wa2, const float* __restrict__ ba2,
             const float* __restrict__ wlat, const float* __restrict__ blat,
             const float* __restrict__ wview, const float* __restrict__ bview,
             const float* __restrict__ wc0, const float* __restrict__ bc0,
             const float* __restrict__ view, const int* __restrict__ ray_id,
             _Float16* __restrict__ pool)
{
    const int id = blockIdx.x * 256 + threadIdx.x;
    if (id >= PREP_TOTAL) return;

    if (id < PREP_W) {
        int r = id; float v = 0.f;
        if (r < 3328) {                                   // WB0 64x52
            int n = r / 52, k = r % 52;
            if (k < 3) v = wb0[k*64+n]; else if (k == 3) v = bb0[n];
            else if (k < 34) v = wb0[(k-1)*64+n];
        } else if (r < 7680) { r -= 3328;                 // WB1 64x68
            int n = r / 68, k = r % 68; if (k < 64) v = wb1[k*64+n];
        } else if (r < 12032) { r -= 7680;                // WB2
            int n = r / 68, k = r % 68; if (k < 64) v = wb2[k*64+n];
        } else if (r < 19456) { r -= 12032;               // WA0 64x116
            int n = r / 116, k = r % 116;
            if (k < 3) v = wa0[k*64+n]; else if (k == 3) v = ba0[n];
            else if (k < 34) v = wa0[(k-1)*64+n];
            else if (k >= 48 && k < 112) v = wa0[(k-15)*64+n];   // 33+(k-48)
        } else if (r < 23808) { r -= 19456;               // WA1
            int n = r / 68, k = r % 68; if (k < 64) v = wa1[k*64+n];
        } else if (r < 28160) { r -= 23808;               // WA2
            int n = r / 68, k = r % 68; if (k < 64) v = wa2[k*64+n];
        } else if (r < 32512) { r -= 28160;               // WLAT
            int n = r / 68, k = r % 68; if (k < 64) v = wlat[k*64+n];
        } else if (r < 35584) { r -= 32512;               // WVIEW 32x96
            int n = r / 96, k = r % 96;
            if (k < 64) v = wview[k*32+n];
            else { int s = k - 64;
                   if (s < 3) v = wview[(64+s)*32+n];
                   else if (s == 3) v = bview[n];
                   else if (s < 22) v = wview[(63+s)*32+n]; }
        } else { r -= 35584;                              // WC0 32x32
            int n = r >> 5, k = r & 31;
            if (n < 16) v = wc0[k*16+n];
        }
        pool[id] = (_Float16)v;
        return;
    }

    if (id < PREP_BT) {                       // bias table f32, C-frag order
        float* bt = (float*)(pool + BTAB_H);
        const int e = id - PREP_W; float v = 0.f;
        if (e < 320) {
            int l = e >> 6, rem = e & 63;
            int mt = rem >> 5, hi2 = (rem >> 4) & 1, q = rem & 15;
            int row = (q & 3) + 8*(q >> 2) + 4*hi2 + 32*mt;
            const float* src[5] = { bb1, bb2, ba1, ba2, blat };
            v = src[l][row];
        } else if (e < 336) {
            int t = e - 320, hi2 = t >> 3, q = t & 7;
            int row = (q & 3) + 8*(q >> 2) + 4*hi2;
            v = bc0[row];
        }
        bt[e] = v;
        return;
    }

    if (id < PREP_IDS) {
        // per-ray vemb row: [vx,vy,vz,1, (s,s,s,c,c,c)*3, 0-pad..31]
        const int ray = id - PREP_BT;
        const float vx = view[3*ray+0], vy = view[3*ray+1], vz = view[3*ray+2];
        u32 w_[16];
        w_[0] = pk(vx, vy); w_[1] = pk(vz, 1.0f);   // slot3=1 -> bias row 67
#pragma unroll
        for (int f = 0; f < 3; ++f) {
            const float fac = (float)(1 << f);
            float sx = __sinf(fac*vx), cx = __cosf(fac*vx);
            float sy = __sinf(fac*vy), cy = __cosf(fac*vy);
            float sz = __sinf(fac*vz), cz = __cosf(fac*vz);
            w_[2+3*f+0] = pk(sx,sy); w_[2+3*f+1] = pk(sz,cx); w_[2+3*f+2] = pk(cy,cz);
        }
#pragma unroll
        for (int i = 11; i < 16; ++i) w_[i] = 0u;
        u32* dst = (u32*)(pool + VTAB_H) + ray * 16;
#pragma unroll
        for (int i = 0; i < 4; ++i)
            ((u32x4*)dst)[i] = (u32x4){w_[4*i], w_[4*i+1], w_[4*i+2], w_[4*i+3]};
        return;
    }

    // ray-start table from sorted ray_id
    {
        const int p = id - PREP_IDS;
        int* tab = (int*)(pool + RAYTAB_H);
        const int cur  = ray_id[p];
        const int prev = (p == 0) ? -1 : ray_id[p-1];
        for (int r = prev + 1; r <= cur; ++r) tab[r] = p;
        if (p == NPTS - 1)
            for (int r = cur + 1; r <= NRAYS; ++r) tab[r] = NPTS;
    }
}

// ================= dense 64->64 from LDS weights ============================
__device__ __forceinline__ void loadBV(f32x16 (&bv)[2], const float* __restrict__ bt,
                                       int l, int hi) {
#pragma unroll
    for (int mt = 0; mt < 2; ++mt) {
        const float* p = bt + l*64 + (mt*2 + hi)*16;
#pragma unroll
        for (int i = 0; i < 4; ++i) {
            f32x4 v = *(const f32x4*)(p + 4*i);
#pragma unroll
            for (int s = 0; s < 4; ++s) bv[mt][4*i + s] = v[s];
        }
    }
}

template<bool RELU>
__device__ __forceinline__ void denseL(const u32* __restrict__ sw, int base,
                                       const f32x16 (&bv)[2], f16x8 (&b)[4][4],
                                       int col, int hi) {
    f16x8 W[2][4];
#pragma unroll
    for (int mt = 0; mt < 2; ++mt)
#pragma unroll
        for (int kc = 0; kc < 4; ++kc)
            W[mt][kc] = ldw(sw, base + (mt*32 + col)*S2_D + kc*8 + hi*4);
#pragma unroll
    for (int t = 0; t < 4; ++t) {
        f32x16 a0 = MFMA32(W[0][0], b[t][0], bv[0]);
        f32x16 a1 = MFMA32(W[1][0], b[t][0], bv[1]);
#pragma unroll
        for (int kc = 1; kc < 4; ++kc) {
            a0 = MFMA32(W[0][kc], b[t][kc], a0);
            a1 = MFMA32(W[1][kc], b[t][kc], a1);
        }
        d2b<RELU>(a0, b[t][0], b[t][1]);
        d2b<RELU>(a1, b[t][2], b[t][3]);
    }
}

// ================= fused MLP: 8-wave block, 128 pts/wave ====================
// One 65 KB LDS weight copy serves 8 waves; 2 blocks/CU -> 4 waves/SIMD.
extern "C" __global__ void __launch_bounds__(512, 2)
mlp_mfma(const float* __restrict__ coor, const int* __restrict__ ray_id,
         const float* __restrict__ wc1, const float* __restrict__ bc1,
         const _Float16* __restrict__ pool, _Float16* __restrict__ rgb)
{
    __shared__ __align__(16) u32 sw[LDS_U32];   // 65,024 B
    const int tid  = threadIdx.x;
    const int lane = tid & 63;
    const int wv   = tid >> 6;                  // 0..7
    const int col  = lane & 31;
    const int hi   = lane >> 5;
    const int wbase = blockIdx.x * 1024 + wv * 128;

    // ---- cooperative weight staging into LDS (8 u32x4 per thread) ----
    {
        const u32x4* pw = (const u32x4*)pool;
        u32x4* dw = (u32x4*)sw;
#pragma unroll
        for (int i = tid; i < LDS_U32/4; i += 512) dw[i] = pw[i];
    }

    int rid[4];
#pragma unroll
    for (int t = 0; t < 4; ++t) rid[t] = ray_id[wbase + 32*t + col];

    // ---- emb B-fragments in-register via permlane32_swap ----
    f16x8 E[4][3];
#pragma unroll
    for (int s = 0; s < 2; ++s) {
        const int pt = wbase + s*64 + lane;
        const float x = coor[3*pt+0], y = coor[3*pt+1], z = coor[3*pt+2];
        u32 w_[17];
        w_[0] = pk(x, y); w_[1] = pk(z, 1.0f);   // slot3=1 -> bias rows
#pragma unroll
        for (int f = 0; f < 5; ++f) {
            const float fac = (float)(1 << f);
            float sx = __sinf(fac*x), cx = __cosf(fac*x);
            float sy = __sinf(fac*y), cy = __cosf(fac*y);
            float sz = __sinf(fac*z), cz = __cosf(fac*z);
            w_[2+3*f+0] = pk(sx,sy); w_[2+3*f+1] = pk(sz,cx); w_[2+3*f+2] = pk(cy,cz);
        }
        // kc 0/1: swap lo/hi word quads -> frag for tile 2s (x') and 2s+1 (y')
#pragma unroll
        for (int kc = 0; kc < 2; ++kc) {
            u32 xw[4], yw[4];
#pragma unroll
            for (int i = 0; i < 4; ++i) {
                xw[i] = w_[kc*8 + i]; yw[i] = w_[kc*8 + 4 + i];
                plswap(xw[i], yw[i]);
            }
            u32x4 lo = {xw[0], xw[1], xw[2], xw[3]};
            u32x4 hw = {yw[0], yw[1], yw[2], yw[3]};
            E[2*s  ][kc] = __builtin_bit_cast(f16x8, lo);
            E[2*s+1][kc] = __builtin_bit_cast(f16x8, hw);
        }
        // kc 2: slots 32,33 word only
        u32 X = w_[16], Y = 0u;
        plswap(X, Y);
        u32x4 e2a = {X, 0u, 0u, 0u}, e2b = {Y, 0u, 0u, 0u};
        E[2*s  ][2] = __builtin_bit_cast(f16x8, e2a);
        E[2*s+1][2] = __builtin_bit_cast(f16x8, e2b);
    }
    __syncthreads();   // weights staged

    const float* bt = (const float*)(pool + BTAB_H);
    const f32x16 Z = zero16();

    f16x8 b[4][4];
    f32x16 bv[2];

    // ---- L0: 3 kc emb frags; bias via slot3 ----
    {
        f16x8 W[2][3];
#pragma unroll
        for (int mt = 0; mt < 2; ++mt)
#pragma unroll
            for (int kc = 0; kc < 3; ++kc)
                W[mt][kc] = ldw(sw, U_WB0 + (mt*32 + col)*S2_WB0 + kc*8 + hi*4);
#pragma unroll
        for (int t = 0; t < 4; ++t) {
            f32x16 a0 = MFMA32(W[0][0], E[t][0], Z);
            f32x16 a1 = MFMA32(W[1][0], E[t][0], Z);
            a0 = MFMA32(W[0][1], E[t][1], a0);
            a1 = MFMA32(W[1][1], E[t][1], a1);
            a0 = MFMA32(W[0][2], E[t][2], a0);
            a1 = MFMA32(W[1][2], E[t][2], a1);
            d2b<true>(a0, b[t][0], b[t][1]);
            d2b<true>(a1, b[t][2], b[t][3]);
        }
    }

    loadBV(bv, bt, 0, hi);
    denseL<true>(sw, U_WB1, bv, b, col, hi);   // d1
    loadBV(bv, bt, 1, hi);
    denseL<true>(sw, U_WB2, bv, b, col, hi);   // d2

    // ---- skip: emb (3 kc, bias via slot3) + h2 (4 kc) ----
    {
        f16x8 We[2][3], Wh[2][4];
#pragma unroll
        for (int mt = 0; mt < 2; ++mt) {
#pragma unroll
            for (int kc = 0; kc < 3; ++kc)
                We[mt][kc] = ldw(sw, U_WA0 + (mt*32 + col)*S2_WA0 + kc*8 + hi*4);
#pragma unroll
            for (int kc = 0; kc < 4; ++kc)
                Wh[mt][kc] = ldw(sw, U_WA0 + (mt*32 + col)*S2_WA0 + 24 + kc*8 + hi*4);
        }
#pragma unroll
        for (int t = 0; t < 4; ++t) {
            f32x16 a0 = MFMA32(We[0][0], E[t][0], Z);
            f32x16 a1 = MFMA32(We[1][0], E[t][0], Z);
            a0 = MFMA32(We[0][1], E[t][1], a0);
            a1 = MFMA32(We[1][1], E[t][1], a1);
            a0 = MFMA32(We[0][2], E[t][2], a0);
            a1 = MFMA32(We[1][2], E[t][2], a1);
#pragma unroll
            for (int kc = 0; kc < 4; ++kc) {
                a0 = MFMA32(Wh[0][kc], b[t][kc], a0);
                a1 = MFMA32(Wh[1][kc], b[t][kc], a1);
            }
            d2b<true>(a0, b[t][0], b[t][1]);
            d2b<true>(a1, b[t][2], b[t][3]);
        }
    }

    loadBV(bv, bt, 2, hi);
    denseL<true>(sw, U_WA1, bv, b, col, hi);   // d3
    loadBV(bv, bt, 3, hi);
    denseL<true>(sw, U_WA2, bv, b, col, hi);   // d4

    // vemb gather (latency hides under lat layer)
    const _Float16* vtab = pool + VTAB_H;
    f16x8 VE[4][2];
#pragma unroll
    for (int t = 0; t < 4; ++t)
#pragma unroll
        for (int kc = 0; kc < 2; ++kc)
            VE[t][kc] = *(const f16x8*)(vtab + rid[t]*32 + kc*16 + hi*8);

    loadBV(bv, bt, 4, hi);
    denseL<false>(sw, U_WLAT, bv, b, col, hi); // latent (no relu)

    // ---- view: lat(4 kc) + vemb(2 kc, bias via vemb slot3); 32 of (global W)
    {
        f16x8 Wv[6];
#pragma unroll
        for (int kc = 0; kc < 6; ++kc)
            Wv[kc] = *(const f16x8*)(pool + WVIEW_H + col*96 + kc*16 + hi*8);
#pragma unroll
        for (int t = 0; t < 4; ++t) {
            f32x16 a = MFMA32(Wv[0], b[t][0], Z);
#pragma unroll
            for (int kc = 1; kc < 4; ++kc) a = MFMA32(Wv[kc], b[t][kc], a);
            a = MFMA32(Wv[4], VE[t][0], a);
            a = MFMA32(Wv[5], VE[t][1], a);
            d2b<true>(a, b[t][0], b[t][1]);
        }
    }

    // ---- c0 (C-init bias) + c1 (16->3) + squash ----
    {
        f16x8 Wc[2];
#pragma unroll
        for (int kc = 0; kc < 2; ++kc)
            Wc[kc] = *(const f16x8*)(pool + WC0_H + col*32 + kc*16 + hi*8);

        f32x16 C = zero16();
        {
            f32x4 c0a = *(const f32x4*)(bt + 320 + hi*8);
            f32x4 c0b = *(const f32x4*)(bt + 320 + hi*8 + 4);
#pragma unroll
            for (int s = 0; s < 4; ++s) { C[s] = c0a[s]; C[4+s] = c0b[s]; }
        }

        float wl[24];
        {
            f32x4 w0 = *(const f32x4*)(wc1 + 12*hi);
            f32x4 w1 = *(const f32x4*)(wc1 + 12*hi + 4);
            f32x4 w2 = *(const f32x4*)(wc1 + 12*hi + 8);
            f32x4 w3 = *(const f32x4*)(wc1 + 24 + 12*hi);
            f32x4 w4 = *(const f32x4*)(wc1 + 24 + 12*hi + 4);
            f32x4 w5 = *(const f32x4*)(wc1 + 24 + 12*hi + 8);
#pragma unroll
            for (int s = 0; s < 4; ++s) {
                wl[s]    = w0[s]; wl[4+s]  = w1[s]; wl[8+s]  = w2[s];
                wl[12+s] = w3[s]; wl[16+s] = w4[s]; wl[20+s] = w5[s];
            }
        }
        const float bo0 = bc1[0], bo1 = bc1[1], bo2 = bc1[2];

#pragma unroll
        for (int t = 0; t < 4; ++t) {
            f32x16 a = MFMA32(Wc[0], b[t][0], C);
            a = MFMA32(Wc[1], b[t][1], a);
            float hc[8];
#pragma unroll
            for (int i = 0; i < 8; ++i) hc[i] = fmaxf(a[i], 0.f);

            float r0 = 0.f, r1 = 0.f, r2 = 0.f;
#pragma unroll
            for (int q = 0; q < 4; ++q) {
                r0 = fmaf(hc[q], wl[3*q+0], fmaf(hc[4+q], wl[12+3*q+0], r0));
                r1 = fmaf(hc[q], wl[3*q+1], fmaf(hc[4+q], wl[12+3*q+1], r1));
                r2 = fmaf(hc[q], wl[3*q+2], fmaf(hc[4+q], wl[12+3*q+2], r2));
            }
            r0 += __shfl_xor(r0, 32);
            r1 += __shfl_xor(r1, 32);
            r2 += __shfl_xor(r2, 32);
            if (hi == 0) {
                const float K2 = 2.8853900817779268f;   // 2*log2(e)
                float e0 = exp2f(K2 * (r0 + bo0));
                float e1 = exp2f(K2 * (r1 + bo1));
                float e2 = exp2f(K2 * (r2 + bo2));
                float v0 = 1.f - __builtin_amdgcn_rcpf(e0 + 1.f);
                float v1 = 1.f - __builtin_amdgcn_rcpf(e1 + 1.f);
                float v2 = 1.f - __builtin_amdgcn_rcpf(e2 + 1.f);
                const int pt = wbase + 32*t + col;
                rgb[3*pt+0] = (_Float16)v0;
                rgb[3*pt+1] = (_Float16)v1;
                rgb[3*pt+2] = (_Float16)v2;
            }
        }
    }
}

// ================= per-ray composite (one wave per ray, table-driven) =======
extern "C" __global__ void __launch_bounds__(256)
composite(const float* __restrict__ raw_density,
          const int*   __restrict__ rtab,
          const _Float16* __restrict__ rgb,
          float*       __restrict__ out)
{
    const int lane = threadIdx.x & 63;
    const int ray  = blockIdx.x * 4 + (threadIdx.x >> 6);

    const int start = rtab[ray];
    const int end   = rtab[ray + 1];

    float carry = 0.0f, a0 = 0.0f, a1 = 0.0f, a2 = 0.0f;

    for (int base = start; base < end; base += 64) {
        const int  idx   = base + lane;
        const bool valid = idx < end;

        float lt = 0.0f, alpha = 0.0f;
        if (valid) {
            const float xx  = raw_density[idx] + ACT_SHIFT_F;
            const float sig = fmaxf(xx, 0.0f) + log1pf(expf(-fabsf(xx)));  // softplus
            lt    = -sig * INTERVAL_F;
            alpha = 1.0f - expf(lt);
        }

        float incl = lt;
#pragma unroll
        for (int d = 1; d < 64; d <<= 1) {
            const float n = __shfl_up(incl, d);
            if (lane >= d) incl += n;
        }

        const float T = expf(carry + (incl - lt));
        if (valid) {
            const float w = T * alpha;
            a0 = fmaf(w, (float)rgb[3*idx+0], a0);
            a1 = fmaf(w, (float)rgb[3*idx+1], a1);
            a2 = fmaf(w, (float)rgb[3*idx+2], a2);
        }
        carry += __shfl(incl, 63);
    }

#pragma unroll
    for (int d = 32; d > 0; d >>= 1) {
        a0 += __shfl_xor(a0, d);
        a1 += __shfl_xor(a1, d);
        a2 += __shfl_xor(a2, d);
    }

    if (lane == 0) {
        const float ainv = expf(carry);
        out[3*ray+0] = a0 + ainv;
        out[3*ray+1] = a1 + ainv;
        out[3*ray+2] = a2 + ainv;
    }
}

// ================= launch ===================================================
extern "C" void kernel_launch(void* const* d_in, const int* in_sizes, int n_in,
                              void* d_out, int out_size, void* d_ws, size_t ws_size,
                              hipStream_t stream) {
    const float* coor        = (const float*)d_in[0];
    const float* view        = (const float*)d_in[1];
    const float* raw_density = (const float*)d_in[2];
    const int*   ray_id      = (const int*)  d_in[3];
    const float* wb0  = (const float*)d_in[4];  const float* bb0  = (const float*)d_in[5];
    const float* wb1  = (const float*)d_in[6];  const float* bb1  = (const float*)d_in[7];
    const float* wb2  = (const float*)d_in[8];  const float* bb2  = (const float*)d_in[9];
    const float* wa0  = (const float*)d_in[10]; const float* ba0  = (const float*)d_in[11];
    const float* wa1  = (const float*)d_in[12]; const float* ba1  = (const float*)d_in[13];
    const float* wa2  = (const float*)d_in[14]; const float* ba2  = (const float*)d_in[15];
    const float* wlat = (const float*)d_in[16]; const float* blat = (const float*)d_in[17];
    const float* wvw  = (const float*)d_in[18]; const float* bvw  = (const float*)d_in[19];
    const float* wc0  = (const float*)d_in[20]; const float* bc0  = (const float*)d_in[21];
    const float* wc1  = (const float*)d_in[22]; const float* bc1  = (const float*)d_in[23];

    _Float16* rgb  = (_Float16*)d_ws;                                   // P*3 f16 = 3.15 MB
    _Float16* pool = (_Float16*)((char*)d_ws + (size_t)NPTS * 3 * 2);
    const int* rtab = (const int*)(pool + RAYTAB_H);

    prep_weights<<<(PREP_TOTAL + 255) / 256, 256, 0, stream>>>(
        wb0, bb0, wb1, bb1, wb2, bb2, wa0, ba0, wa1, ba1, wa2, ba2,
        wlat, blat, wvw, bvw, wc0, bc0, view, ray_id, pool);

    mlp_mfma<<<NPTS / 1024, 512, 0, stream>>>(
        coor, ray_id, wc1, bc1, pool, rgb);

    composite<<<NRAYS / 4, 256, 0, stream>>>(raw_density, rtab, rgb, (float*)d_out);
}

// Round 13
// 52.011 us; speedup vs baseline: 1.4537x; 1.0009x over previous
//
#include <hip/hip_runtime.h>
#include <math.h>

#define NPTS  524288
#define NRAYS 4096
#define ACT_SHIFT_F (-2.1972245773362196f)   // log(1/(1-0.1) - 1)
#define INTERVAL_F  0.5f

typedef _Float16 f16x8  __attribute__((ext_vector_type(8)));
typedef __fp16   fp16x2 __attribute__((ext_vector_type(2)));
typedef float    f32x4  __attribute__((ext_vector_type(4)));
typedef float    f32x16 __attribute__((ext_vector_type(16)));
typedef int      i32x2  __attribute__((ext_vector_type(2)));
typedef unsigned u32;
typedef unsigned u32x4  __attribute__((ext_vector_type(4)));

#define MFMA32(a,b,c) __builtin_amdgcn_mfma_f32_32x32x16_f16((a),(b),(c),0,0,0)

// ---- pool: FRAGMENT-ORDER weights. frag(kc,mt,lane) 8 halves at
//   base + ((kc*MT+mt)*64 + lane)*8.  lane=(hi<<5)|col; of=mt*32+col;
//   k=kc*16+hi*8+j.  Biases all via btab C-init (emb/vemb bias slots dead).
// half offsets:
#define FB0_H   0        // WB0 3 kc x 2 mt          (3072)
#define FD1_H   3072     // wb1 4 kc x 2              (4096)
#define FD2_H   7168     // wb2                       (4096)
#define FA0_H   11264    // wa0 7 kc x 2              (7168)
#define FD3_H   18432    // wa1                       (4096)
#define FD4_H   22528    // wa2                       (4096)
#define FLAT_H  26624    // wlat                      (4096)
#define LDSW_H  30720    // end of LDS-resident region (61440 B)
#define FVIEW_H 30720    // wview 6 kc x 1 mt         (3072)
#define FC0_H   33792    // wc0 2 kc x 1 mt           (1024)
#define BTAB_H  34816    // 512 f32 (1024 halves)
#define VTAB_H  35840    // 4096 rays x 32 halves
#define RAYTAB_H 166912  // (NRAYS+1) ints

#define PREP_W    34816
#define PREP_BT   (PREP_W + 512)        // 35328
#define PREP_IDS  (PREP_BT + NRAYS)     // 39424
#define PREP_TOTAL (PREP_IDS + NPTS)

// u32 offsets inside LDS for fragment bases
#define UB0  0
#define UD1  1536
#define UD2  3584
#define UA0  5632
#define UD3  9216
#define UD4  11264
#define ULAT 13312
#define LDS_U32 15360    // 61440 B

// ================= helpers ==================================================
__device__ __forceinline__ u32 pk(float a, float b) {
    fp16x2 h = __builtin_amdgcn_cvt_pkrtz(a, b);
    return __builtin_bit_cast(u32, h);
}

__device__ __forceinline__ void plswap(u32 &x, u32 &y) {
    i32x2 r = __builtin_amdgcn_permlane32_swap((int)x, (int)y, false, false);
    x = (u32)r[0]; y = (u32)r[1];
}

template<bool RELU>
__device__ __forceinline__ f16x8 reluq(f16x8 v) {
    if (RELU) {
        f16x8 z = {};
        return __builtin_elementwise_max(v, z);   // v_pk_max_f16 x4
    }
    return v;
}

// D(32x32 tile) -> two B k-chunk fragments of next layer (HW-verified r5-r12)
template<bool RELU>
__device__ __forceinline__ void d2b(f32x16 a, f16x8 &blo, f16x8 &bhi) {
    u32 p0 = pk(a[0],a[1]),   p1 = pk(a[2],a[3]);
    u32 p2 = pk(a[4],a[5]),   p3 = pk(a[6],a[7]);
    plswap(p0, p2); plswap(p1, p3);
    u32x4 lo = {p0, p1, p2, p3};
    blo = reluq<RELU>(__builtin_bit_cast(f16x8, lo));
    u32 p4 = pk(a[8],a[9]),   p5 = pk(a[10],a[11]);
    u32 p6 = pk(a[12],a[13]), p7 = pk(a[14],a[15]);
    plswap(p4, p6); plswap(p5, p7);
    u32x4 hw = {p4, p5, p6, p7};
    bhi = reluq<RELU>(__builtin_bit_cast(f16x8, hw));
}

// fragment from LDS: ONE ds_read_b128 at lane*16 + imm (conflict-free)
__device__ __forceinline__ f16x8 ldf(const u32* __restrict__ swl, int imm) {
    return __builtin_bit_cast(f16x8, *(const u32x4*)(swl + imm));
}

// ================= prep: fragment-order weights + btab + vemb + raytab ======
extern "C" __global__ void __launch_bounds__(256)
prep_weights(const float* __restrict__ wb0, const float* __restrict__ bb0,
             const float* __restrict__ wb1, const float* __restrict__ bb1,
             const float* __restrict__ wb2, const float* __restrict__ bb2,
             const float* __restrict__ wa0, const float* __restrict__ ba0,
             const float* __restrict__ wa1, const float* __restrict__ ba1,
             const float* __restrict__ wa2, const float* __restrict__ ba2,
             const float* __restrict__ wlat, const float* __restrict__ blat,
             const float* __restrict__ wview, const float* __restrict__ bview,
             const float* __restrict__ wc0, const float* __restrict__ bc0,
             const float* __restrict__ view, const int* __restrict__ ray_id,
             _Float16* __restrict__ pool)
{
    const int id = blockIdx.x * 256 + threadIdx.x;
    if (id >= PREP_TOTAL) return;

    if (id < PREP_W) {
        int r = id; float v = 0.f;
        if (r < 33792) {   // two-mt fragment layers + view (handled below)
            const float* W; int base, MT;
            if      (r < 3072)  { W = wb0;  base = 0;     MT = 2; }
            else if (r < 7168)  { W = wb1;  base = 3072;  MT = 2; }
            else if (r < 11264) { W = wb2;  base = 7168;  MT = 2; }
            else if (r < 18432) { W = wa0;  base = 11264; MT = 2; }
            else if (r < 22528) { W = wa1;  base = 18432; MT = 2; }
            else if (r < 26624) { W = wa2;  base = 22528; MT = 2; }
            else if (r < 30720) { W = wlat; base = 26624; MT = 2; }
            else                { W = wview;base = 30720; MT = 1; }
            const int e    = r - base;
            const int j    = e & 7;
            const int lane = (e >> 3) & 63;
            const int col  = lane & 31, hi = lane >> 5;
            int kc, mt;
            if (MT == 2) { kc = e >> 10; mt = (e >> 9) & 1; }
            else         { kc = e >> 9;  mt = 0; }
            const int of = mt * 32 + col;
            const int k  = kc * 16 + hi * 8 + j;
            if (W == wb0) {                       // emb-slot K=48
                if (k < 3) v = wb0[k*64+of];
                else if (k >= 4 && k < 34) v = wb0[(k-1)*64+of];
            } else if (W == wa0) {                // emb slots + h2, K=112
                if (k < 3) v = wa0[k*64+of];
                else if (k >= 4 && k < 34) v = wa0[(k-1)*64+of];
                else if (k >= 48 && k < 112) v = wa0[(k-15)*64+of];
            } else if (W == wview) {              // lat + vemb slots, K=96
                if (k < 64) v = wview[k*32+of];
                else { int s = k - 64;
                       if (s < 3) v = wview[(64+s)*32+of];
                       else if (s >= 4 && s < 22) v = wview[(63+s)*32+of]; }
            } else {                              // plain dense K=64
                if (k < 64) v = W[k*64+of];
            }
            pool[id] = (_Float16)v;
        } else {                                  // WC0 fragment-order
            const int e = r - 33792;
            const int j = e & 7;
            const int lane = (e >> 3) & 63;
            const int col = lane & 31, hi = lane >> 5;
            const int kc = e >> 9;
            const int k = kc * 16 + hi * 8 + j;
            float v2 = (col < 16 && k < 32) ? wc0[k*16+col] : 0.f;
            pool[id] = (_Float16)v2;
        }
        return;
    }

    if (id < PREP_BT) {                  // btab f32: 7x64 + view 32 + c0 16
        float* bt = (float*)(pool + BTAB_H);
        const int e = id - PREP_W; float v = 0.f;
        if (e < 448) {
            int l = e >> 6, rem = e & 63;
            int mt = rem >> 5, hi2 = (rem >> 4) & 1, q = rem & 15;
            int row = (q & 3) + 8*(q >> 2) + 4*hi2 + 32*mt;
            const float* src[7] = { bb0, bb1, bb2, ba0, ba1, ba2, blat };
            v = src[l][row];
        } else if (e < 480) {
            int t = e - 448, hi2 = t >> 4, q = t & 15;
            int row = (q & 3) + 8*(q >> 2) + 4*hi2;
            v = bview[row];
        } else if (e < 496) {
            int t = e - 480, hi2 = t >> 3, q = t & 7;
            int row = (q & 3) + 8*(q >> 2) + 4*hi2;
            v = bc0[row];
        }
        bt[e] = v;
        return;
    }

    if (id < PREP_IDS) {
        // per-ray vemb row: [vx,vy,vz,0, (s,s,s,c,c,c)*3, 0-pad..31]
        const int ray = id - PREP_BT;
        const float vx = view[3*ray+0], vy = view[3*ray+1], vz = view[3*ray+2];
        u32 w_[16];
        w_[0] = pk(vx, vy); w_[1] = pk(vz, 0.f);
#pragma unroll
        for (int f = 0; f < 3; ++f) {
            const float fac = (float)(1 << f);
            float sx = __sinf(fac*vx), cx = __cosf(fac*vx);
            float sy = __sinf(fac*vy), cy = __cosf(fac*vy);
            float sz = __sinf(fac*vz), cz = __cosf(fac*vz);
            w_[2+3*f+0] = pk(sx,sy); w_[2+3*f+1] = pk(sz,cx); w_[2+3*f+2] = pk(cy,cz);
        }
#pragma unroll
        for (int i = 11; i < 16; ++i) w_[i] = 0u;
        u32* dst = (u32*)(pool + VTAB_H) + ray * 16;
#pragma unroll
        for (int i = 0; i < 4; ++i)
            ((u32x4*)dst)[i] = (u32x4){w_[4*i], w_[4*i+1], w_[4*i+2], w_[4*i+3]};
        return;
    }

    // ray-start table from sorted ray_id
    {
        const int p = id - PREP_IDS;
        int* tab = (int*)(pool + RAYTAB_H);
        const int cur  = ray_id[p];
        const int prev = (p == 0) ? -1 : ray_id[p-1];
        for (int r = prev + 1; r <= cur; ++r) tab[r] = p;
        if (p == NPTS - 1)
            for (int r = cur + 1; r <= NRAYS; ++r) tab[r] = NPTS;
    }
}

// ================= compute helpers ==========================================
__device__ __forceinline__ void loadBV(f32x16 (&bv)[2], const float* __restrict__ bt,
                                       int l, int hi) {
#pragma unroll
    for (int mt = 0; mt < 2; ++mt) {
        const float* p = bt + l*64 + (mt*2 + hi)*16;
#pragma unroll
        for (int i = 0; i < 4; ++i) {
            f32x4 v = *(const f32x4*)(p + 4*i);
#pragma unroll
            for (int s = 0; s < 4; ++s) bv[mt][4*i + s] = v[s];
        }
    }
}

template<bool RELU>
__device__ __forceinline__ void denseL(const u32* __restrict__ swl, int base,
                                       const f32x16 (&bv)[2], f16x8 (&b)[4][4]) {
    f16x8 W[2][4];
#pragma unroll
    for (int mt = 0; mt < 2; ++mt)
#pragma unroll
        for (int kc = 0; kc < 4; ++kc)
            W[mt][kc] = ldf(swl, base + (kc*2 + mt)*256);
#pragma unroll
    for (int t = 0; t < 4; ++t) {
        f32x16 a0 = MFMA32(W[0][0], b[t][0], bv[0]);
        f32x16 a1 = MFMA32(W[1][0], b[t][0], bv[1]);
#pragma unroll
        for (int kc = 1; kc < 4; ++kc) {
            a0 = MFMA32(W[0][kc], b[t][kc], a0);
            a1 = MFMA32(W[1][kc], b[t][kc], a1);
        }
        d2b<RELU>(a0, b[t][0], b[t][1]);
        d2b<RELU>(a1, b[t][2], b[t][3]);
    }
}

// ================= fused MLP: 8-wave block, 128 pts/wave ====================
extern "C" __global__ void __launch_bounds__(512, 2)
mlp_mfma(const float* __restrict__ coor, const int* __restrict__ ray_id,
         const float* __restrict__ wc1, const float* __restrict__ bc1,
         const _Float16* __restrict__ pool, _Float16* __restrict__ rgb)
{
    __shared__ __align__(16) u32 sw[LDS_U32];   // 61,440 B
    const int tid  = threadIdx.x;
    const int lane = tid & 63;
    const int wv   = tid >> 6;                  // 0..7
    const int col  = lane & 31;
    const int hi   = lane >> 5;
    const int wbase = blockIdx.x * 1024 + wv * 128;

    // ---- cooperative weight staging into LDS ----
    {
        const u32x4* pw = (const u32x4*)pool;
        u32x4* dw = (u32x4*)sw;
#pragma unroll
        for (int i = tid; i < LDS_U32/4; i += 512) dw[i] = pw[i];
    }

    int rid[4];
#pragma unroll
    for (int t = 0; t < 4; ++t) rid[t] = ray_id[wbase + 32*t + col];

    // ---- emb B-fragments in-register via permlane32_swap ----
    f16x8 E[4][3];
#pragma unroll
    for (int s = 0; s < 2; ++s) {
        const int pt = wbase + s*64 + lane;
        const float x = coor[3*pt+0], y = coor[3*pt+1], z = coor[3*pt+2];
        u32 w_[17];
        w_[0] = pk(x, y); w_[1] = pk(z, 0.f);
#pragma unroll
        for (int f = 0; f < 5; ++f) {
            const float fac = (float)(1 << f);
            float sx = __sinf(fac*x), cx = __cosf(fac*x);
            float sy = __sinf(fac*y), cy = __cosf(fac*y);
            float sz = __sinf(fac*z), cz = __cosf(fac*z);
            w_[2+3*f+0] = pk(sx,sy); w_[2+3*f+1] = pk(sz,cx); w_[2+3*f+2] = pk(cy,cz);
        }
#pragma unroll
        for (int kc = 0; kc < 2; ++kc) {
            u32 xw[4], yw[4];
#pragma unroll
            for (int i = 0; i < 4; ++i) {
                xw[i] = w_[kc*8 + i]; yw[i] = w_[kc*8 + 4 + i];
                plswap(xw[i], yw[i]);
            }
            u32x4 lo = {xw[0], xw[1], xw[2], xw[3]};
            u32x4 hw = {yw[0], yw[1], yw[2], yw[3]};
            E[2*s  ][kc] = __builtin_bit_cast(f16x8, lo);
            E[2*s+1][kc] = __builtin_bit_cast(f16x8, hw);
        }
        u32 X = w_[16], Y = 0u;
        plswap(X, Y);
        u32x4 e2a = {X, 0u, 0u, 0u}, e2b = {Y, 0u, 0u, 0u};
        E[2*s  ][2] = __builtin_bit_cast(f16x8, e2a);
        E[2*s+1][2] = __builtin_bit_cast(f16x8, e2b);
    }
    __syncthreads();   // weights staged

    const u32* swl = sw + lane * 4;            // per-lane fragment base
    const float* bt = (const float*)(pool + BTAB_H);

    f16x8 b[4][4];
    f32x16 bv[2];

    // ---- L0: 3 kc emb frags; bias = C-init (btab l=0) ----
    {
        f16x8 W[2][3];
#pragma unroll
        for (int mt = 0; mt < 2; ++mt)
#pragma unroll
            for (int kc = 0; kc < 3; ++kc)
                W[mt][kc] = ldf(swl, UB0 + (kc*2 + mt)*256);
        loadBV(bv, bt, 0, hi);
#pragma unroll
        for (int t = 0; t < 4; ++t) {
            f32x16 a0 = MFMA32(W[0][0], E[t][0], bv[0]);
            f32x16 a1 = MFMA32(W[1][0], E[t][0], bv[1]);
            a0 = MFMA32(W[0][1], E[t][1], a0);
            a1 = MFMA32(W[1][1], E[t][1], a1);
            a0 = MFMA32(W[0][2], E[t][2], a0);
            a1 = MFMA32(W[1][2], E[t][2], a1);
            d2b<true>(a0, b[t][0], b[t][1]);
            d2b<true>(a1, b[t][2], b[t][3]);
        }
    }

    loadBV(bv, bt, 1, hi);
    denseL<true>(swl, UD1, bv, b);   // d1
    loadBV(bv, bt, 2, hi);
    denseL<true>(swl, UD2, bv, b);   // d2

    // ---- skip: emb (kc0..2) + h2 (kc3..6); bias = C-init (btab l=3) ----
    {
        f16x8 We[2][3], Wh[2][4];
#pragma unroll
        for (int mt = 0; mt < 2; ++mt) {
#pragma unroll
            for (int kc = 0; kc < 3; ++kc)
                We[mt][kc] = ldf(swl, UA0 + (kc*2 + mt)*256);
#pragma unroll
            for (int kc = 0; kc < 4; ++kc)
                Wh[mt][kc] = ldf(swl, UA0 + ((kc+3)*2 + mt)*256);
        }
        loadBV(bv, bt, 3, hi);
#pragma unroll
        for (int t = 0; t < 4; ++t) {
            f32x16 a0 = MFMA32(We[0][0], E[t][0], bv[0]);
            f32x16 a1 = MFMA32(We[1][0], E[t][0], bv[1]);
            a0 = MFMA32(We[0][1], E[t][1], a0);
            a1 = MFMA32(We[1][1], E[t][1], a1);
            a0 = MFMA32(We[0][2], E[t][2], a0);
            a1 = MFMA32(We[1][2], E[t][2], a1);
#pragma unroll
            for (int kc = 0; kc < 4; ++kc) {
                a0 = MFMA32(Wh[0][kc], b[t][kc], a0);
                a1 = MFMA32(Wh[1][kc], b[t][kc], a1);
            }
            d2b<true>(a0, b[t][0], b[t][1]);
            d2b<true>(a1, b[t][2], b[t][3]);
        }
    }

    loadBV(bv, bt, 4, hi);
    denseL<true>(swl, UD3, bv, b);   // d3
    loadBV(bv, bt, 5, hi);
    denseL<true>(swl, UD4, bv, b);   // d4

    // vemb gather (latency hides under lat layer)
    const _Float16* vtab = pool + VTAB_H;
    f16x8 VE[4][2];
#pragma unroll
    for (int t = 0; t < 4; ++t)
#pragma unroll
        for (int kc = 0; kc < 2; ++kc)
            VE[t][kc] = *(const f16x8*)(vtab + rid[t]*32 + kc*16 + hi*8);

    loadBV(bv, bt, 6, hi);
    denseL<false>(swl, ULAT, bv, b); // latent (no relu)

    // ---- view: lat(4 kc) + vemb(2 kc); 32 of; bias = C-init ----
    {
        f16x8 Wv[6];
#pragma unroll
        for (int kc = 0; kc < 6; ++kc)
            Wv[kc] = *(const f16x8*)(pool + FVIEW_H + (kc*64 + lane)*8);
        f32x16 bvv;
        {
            const float* p = bt + 448 + hi*16;
#pragma unroll
            for (int i = 0; i < 4; ++i) {
                f32x4 v = *(const f32x4*)(p + 4*i);
#pragma unroll
                for (int s = 0; s < 4; ++s) bvv[4*i + s] = v[s];
            }
        }
#pragma unroll
        for (int t = 0; t < 4; ++t) {
            f32x16 a = MFMA32(Wv[0], b[t][0], bvv);
#pragma unroll
            for (int kc = 1; kc < 4; ++kc) a = MFMA32(Wv[kc], b[t][kc], a);
            a = MFMA32(Wv[4], VE[t][0], a);
            a = MFMA32(Wv[5], VE[t][1], a);
            d2b<true>(a, b[t][0], b[t][1]);
        }
    }

    // ---- c0 (bias C-init) + c1 (16->3) + squash ----
    {
        f16x8 Wc[2];
#pragma unroll
        for (int kc = 0; kc < 2; ++kc)
            Wc[kc] = *(const f16x8*)(pool + FC0_H + (kc*64 + lane)*8);

        f32x16 C;
        {
            f32x4 c0a = *(const f32x4*)(bt + 480 + hi*8);
            f32x4 c0b = *(const f32x4*)(bt + 480 + hi*8 + 4);
#pragma unroll
            for (int s = 0; s < 4; ++s) {
                C[s] = c0a[s]; C[4+s] = c0b[s]; C[8+s] = 0.f; C[12+s] = 0.f;
            }
        }

        float wl[24];
        {
            f32x4 w0 = *(const f32x4*)(wc1 + 12*hi);
            f32x4 w1 = *(const f32x4*)(wc1 + 12*hi + 4);
            f32x4 w2 = *(const f32x4*)(wc1 + 12*hi + 8);
            f32x4 w3 = *(const f32x4*)(wc1 + 24 + 12*hi);
            f32x4 w4 = *(const f32x4*)(wc1 + 24 + 12*hi + 4);
            f32x4 w5 = *(const f32x4*)(wc1 + 24 + 12*hi + 8);
#pragma unroll
            for (int s = 0; s < 4; ++s) {
                wl[s]    = w0[s]; wl[4+s]  = w1[s]; wl[8+s]  = w2[s];
                wl[12+s] = w3[s]; wl[16+s] = w4[s]; wl[20+s] = w5[s];
            }
        }
        const float bo0 = bc1[0], bo1 = bc1[1], bo2 = bc1[2];

#pragma unroll
        for (int t = 0; t < 4; ++t) {
            f32x16 a = MFMA32(Wc[0], b[t][0], C);
            a = MFMA32(Wc[1], b[t][1], a);
            float hc[8];
#pragma unroll
            for (int i = 0; i < 8; ++i) hc[i] = fmaxf(a[i], 0.f);

            float r0 = 0.f, r1 = 0.f, r2 = 0.f;
#pragma unroll
            for (int q = 0; q < 4; ++q) {
                r0 = fmaf(hc[q], wl[3*q+0], fmaf(hc[4+q], wl[12+3*q+0], r0));
                r1 = fmaf(hc[q], wl[3*q+1], fmaf(hc[4+q], wl[12+3*q+1], r1));
                r2 = fmaf(hc[q], wl[3*q+2], fmaf(hc[4+q], wl[12+3*q+2], r2));
            }
            r0 += __shfl_xor(r0, 32);
            r1 += __shfl_xor(r1, 32);
            r2 += __shfl_xor(r2, 32);
            if (hi == 0) {
                const float K2 = 2.8853900817779268f;   // 2*log2(e)
                float e0 = exp2f(K2 * (r0 + bo0));
                float e1 = exp2f(K2 * (r1 + bo1));
                float e2 = exp2f(K2 * (r2 + bo2));
                float v0 = 1.f - __builtin_amdgcn_rcpf(e0 + 1.f);
                float v1 = 1.f - __builtin_amdgcn_rcpf(e1 + 1.f);
                float v2 = 1.f - __builtin_amdgcn_rcpf(e2 + 1.f);
                const int pt = wbase + 32*t + col;
                rgb[3*pt+0] = (_Float16)v0;
                rgb[3*pt+1] = (_Float16)v1;
                rgb[3*pt+2] = (_Float16)v2;
            }
        }
    }
}

// ================= per-ray composite (one wave per ray, table-driven) =======
extern "C" __global__ void __launch_bounds__(256)
composite(const float* __restrict__ raw_density,
          const int*   __restrict__ rtab,
          const _Float16* __restrict__ rgb,
          float*       __restrict__ out)
{
    const int lane = threadIdx.x & 63;
    const int ray  = blockIdx.x * 4 + (threadIdx.x >> 6);

    const int start = rtab[ray];
    const int end   = rtab[ray + 1];

    float carry = 0.0f, a0 = 0.0f, a1 = 0.0f, a2 = 0.0f;

    for (int base = start; base < end; base += 64) {
        const int  idx   = base + lane;
        const bool valid = idx < end;

        float lt = 0.0f, alpha = 0.0f;
        if (valid) {
            const float xx  = raw_density[idx] + ACT_SHIFT_F;
            const float sig = fmaxf(xx, 0.0f) + log1pf(expf(-fabsf(xx)));  // softplus
            lt    = -sig * INTERVAL_F;
            alpha = 1.0f - expf(lt);
        }

        float incl = lt;
#pragma unroll
        for (int d = 1; d < 64; d <<= 1) {
            const float n = __shfl_up(incl, d);
            if (lane >= d) incl += n;
        }

        const float T = expf(carry + (incl - lt));
        if (valid) {
            const float w = T * alpha;
            a0 = fmaf(w, (float)rgb[3*idx+0], a0);
            a1 = fmaf(w, (float)rgb[3*idx+1], a1);
            a2 = fmaf(w, (float)rgb[3*idx+2], a2);
        }
        carry += __shfl(incl, 63);
    }

#pragma unroll
    for (int d = 32; d > 0; d >>= 1) {
        a0 += __shfl_xor(a0, d);
        a1 += __shfl_xor(a1, d);
        a2 += __shfl_xor(a2, d);
    }

    if (lane == 0) {
        const float ainv = expf(carry);
        out[3*ray+0] = a0 + ainv;
        out[3*ray+1] = a1 + ainv;
        out[3*ray+2] = a2 + ainv;
    }
}

// ================= launch ===================================================
extern "C" void kernel_launch(void* const* d_in, const int* in_sizes, int n_in,
                              void* d_out, int out_size, void* d_ws, size_t ws_size,
                              hipStream_t stream) {
    const float* coor        = (const float*)d_in[0];
    const float* view        = (const float*)d_in[1];
    const float* raw_density = (const float*)d_in[2];
    const int*   ray_id      = (const int*)  d_in[3];
    const float* wb0  = (const float*)d_in[4];  const float* bb0  = (const float*)d_in[5];
    const float* wb1  = (const float*)d_in[6];  const float* bb1  = (const float*)d_in[7];
    const float* wb2  = (const float*)d_in[8];  const float* bb2  = (const float*)d_in[9];
    const float* wa0  = (const float*)d_in[10]; const float* ba0  = (const float*)d_in[11];
    const float* wa1  = (const float*)d_in[12]; const float* ba1  = (const float*)d_in[13];
    const float* wa2  = (const float*)d_in[14]; const float* ba2  = (const float*)d_in[15];
    const float* wlat = (const float*)d_in[16]; const float* blat = (const float*)d_in[17];
    const float* wvw  = (const float*)d_in[18]; const float* bvw  = (const float*)d_in[19];
    const float* wc0  = (const float*)d_in[20]; const float* bc0  = (const float*)d_in[21];
    const float* wc1  = (const float*)d_in[22]; const float* bc1  = (const float*)d_in[23];

    _Float16* rgb  = (_Float16*)d_ws;                                   // P*3 f16 = 3.15 MB
    _Float16* pool = (_Float16*)((char*)d_ws + (size_t)NPTS * 3 * 2);
    const int* rtab = (const int*)(pool + RAYTAB_H);

    prep_weights<<<(PREP_TOTAL + 255) / 256, 256, 0, stream>>>(
        wb0, bb0, wb1, bb1, wb2, bb2, wa0, ba0, wa1, ba1, wa2, ba2,
        wlat, blat, wvw, bvw, wc0, bc0, view, ray_id, pool);

    mlp_mfma<<<NPTS / 1024, 512, 0, stream>>>(
        coor, ray_id, wc1, bc1, pool, rgb);

    composite<<<NRAYS / 4, 256, 0, stream>>>(raw_density, rtab, rgb, (float*)d_out);
}